// Round 7
// baseline (1144.678 us; speedup 1.0000x reference)
//
#include <hip/hip_runtime.h>

#define N_NODES 50000
#define HID 128
#define NE 1600000
#define NH (N_NODES * HID)      // 6,400,000 floats per [N,HID] buffer

#define EPB   4096              // edges per K1/K3 block
#define NBLK1 391               // ceil(NE / EPB)
#define NBUK  391               // ceil(N_NODES / 128) row buckets (128 rows each)
#define TBL   (NBUK * NBLK1)    // 152,881 scan table entries
#define SB    ((TBL + 255) / 256)  // 598 scan blocks

#define N4F   (N_NODES * 4)     // float4s per 16-col slice
#define RBS   ((N_NODES + 63) / 64)  // 782 row-blocks per slice

// ===========================================================================
// K1: per-block LDS histogram over 391 coarse buckets + per-edge rank.
// ===========================================================================
__global__ __launch_bounds__(256) void k1_hist(
    const int* __restrict__ rows, int* __restrict__ table,
    unsigned short* __restrict__ rank)
{
    __shared__ int h[NBUK];
    int b = blockIdx.x, t = threadIdx.x;
    for (int i = t; i < NBUK; i += 256) h[i] = 0;
    __syncthreads();
    int e0 = b * EPB;
    int e1 = min(e0 + EPB, NE);
    for (int e = e0 + t; e < e1; e += 256)
        rank[e] = (unsigned short)atomicAdd(&h[rows[e] >> 7], 1);
    __syncthreads();
    for (int i = t; i < NBUK; i += 256) table[i * NBLK1 + b] = h[i];
}

// ===========================================================================
// S1/S2/S3: hierarchical exclusive scan of table[TBL] (bucket-major)
// ===========================================================================
__global__ __launch_bounds__(256) void s1_partial(
    const int* __restrict__ table, int* __restrict__ part)
{
    __shared__ int red[256];
    int b = blockIdx.x, t = threadIdx.x;
    int idx = b * 256 + t;
    red[t] = (idx < TBL) ? table[idx] : 0;
    __syncthreads();
    #pragma unroll
    for (int s = 128; s > 0; s >>= 1) {
        if (t < s) red[t] += red[t + s];
        __syncthreads();
    }
    if (t == 0) part[b] = red[0];
}

__global__ __launch_bounds__(1024) void s2_scan(int* __restrict__ part)
{
    __shared__ int sh[1024];
    int t = threadIdx.x;
    sh[t] = (t < SB) ? part[t] : 0;
    __syncthreads();
    for (int off = 1; off < 1024; off <<= 1) {
        int v = (t >= off) ? sh[t - off] : 0;
        __syncthreads();
        sh[t] += v;
        __syncthreads();
    }
    if (t < SB) part[t] = (t == 0) ? 0 : sh[t - 1];
}

__global__ __launch_bounds__(256) void s3_add(
    int* __restrict__ table, const int* __restrict__ part)
{
    __shared__ int sh[256];
    int b = blockIdx.x, t = threadIdx.x;
    int idx = b * 256 + t;
    int v = (idx < TBL) ? table[idx] : 0;
    sh[t] = v;
    __syncthreads();
    #pragma unroll
    for (int off = 1; off < 256; off <<= 1) {
        int u = (t >= off) ? sh[t - off] : 0;
        __syncthreads();
        sh[t] += u;
        __syncthreads();
    }
    int excl = (t == 0) ? 0 : sh[t - 1];
    if (idx < TBL) table[idx] = part[b] + excl;
}

// ===========================================================================
// K3: atomic-free scatter into bucket-partitioned tmp.
// word0 = (row&127)<<16 | col  (col < 65536), word1 = val bits.
// ===========================================================================
__global__ __launch_bounds__(256) void k3_scatter(
    const int* __restrict__ rows, const int* __restrict__ cols,
    const float* __restrict__ vals, const unsigned short* __restrict__ rank,
    const int* __restrict__ table, int2* __restrict__ tmp)
{
    __shared__ int base[NBUK];
    int b = blockIdx.x, t = threadIdx.x;
    for (int i = t; i < NBUK; i += 256) base[i] = table[i * NBLK1 + b];
    __syncthreads();
    int e0 = b * EPB;
    int e1 = min(e0 + EPB, NE);
    for (int e = e0 + t; e < e1; e += 256) {
        int r = rows[e];
        int pos = base[r >> 7] + (int)rank[e];
        tmp[pos] = make_int2(((r & 127) << 16) | cols[e], __float_as_int(vals[e]));
    }
}

// ===========================================================================
// K4: per-bucket fine sort (128 rows) -> final CSR pairs + rowptr.
// ===========================================================================
__global__ __launch_bounds__(256) void k4_fine(
    const int* __restrict__ table, const int2* __restrict__ tmp,
    int2* __restrict__ pairs, int* __restrict__ rowptr)
{
    __shared__ int cnt[128];
    __shared__ int sh[256];
    __shared__ int nxt[128];
    int k = blockIdx.x, t = threadIdx.x;
    if (t < 128) cnt[t] = 0;
    __syncthreads();
    int base = table[k * NBLK1];
    int end  = (k == NBUK - 1) ? NE : table[(k + 1) * NBLK1];
    for (int e = base + t; e < end; e += 256)
        atomicAdd(&cnt[(tmp[e].x >> 16) & 127], 1);
    __syncthreads();
    sh[t] = (t < 128) ? cnt[t] : 0;
    __syncthreads();
    #pragma unroll
    for (int off = 1; off < 256; off <<= 1) {
        int v = (t >= off) ? sh[t - off] : 0;
        __syncthreads();
        sh[t] += v;
        __syncthreads();
    }
    if (t < 128) {
        int excl = (t == 0) ? 0 : sh[t - 1];
        nxt[t] = base + excl;
        int row = k * 128 + t;
        if (row < N_NODES) rowptr[row] = base + excl;
    }
    if (k == NBUK - 1 && t == 255) rowptr[N_NODES] = NE;
    __syncthreads();
    for (int e = base + t; e < end; e += 256) {
        int2 p = tmp[e];
        int pos = atomicAdd(&nxt[(p.x >> 16) & 127], 1);
        pairs[pos] = make_int2(p.x & 0xFFFF, p.y);
    }
}

// ===========================================================================
// Transform standard [N][128] -> slice-major [8][N][16]
// ===========================================================================
__global__ __launch_bounds__(256) void to_slices_kernel(
    const float* __restrict__ x, float* __restrict__ xs)
{
    int idx = blockIdx.x * 256 + threadIdx.x;    // float4 id
    if (idx >= N_NODES * 32) return;
    int n = idx >> 5, q = idx & 31;
    float4 v = ((const float4*)x)[idx];
    ((float4*)xs)[(size_t)(q >> 2) * N4F + (size_t)n * 4 + (q & 3)] = v;
}

// ===========================================================================
// Column-sliced CSR SpMM, XCD-pinned.
// blockIdx.x = rb*8 + s; s = slice (16 cols) -> pinned to XCD s via
// round-robin dispatch. 4 lanes per (row, slice), 64 rows per block.
// Source layout: STD ? standard [N][128] : slice-major [8][N][16].
// Output ys is ALWAYS slice-major.
// ===========================================================================
template <bool ABS, bool STD>
__global__ __launch_bounds__(256) void csr_spmm_kernel(
    const int* __restrict__ rowptr, const int2* __restrict__ pairs,
    const float* __restrict__ x, float* __restrict__ ys)
{
    const int s   = blockIdx.x & 7;
    const int rb  = blockIdx.x >> 3;
    const int g   = threadIdx.x >> 2;
    const int sub = threadIdx.x & 3;
    const int r   = rb * 64 + g;
    if (r >= N_NODES) return;

    const float4* x4 = (const float4*)x +
        (STD ? (size_t)(s * 4 + sub) : (size_t)s * N4F + sub);
    const int cs = STD ? 32 : 4;   // float4 stride per column index

    int start = rowptr[r], end = rowptr[r + 1];

    float4 a0 = {0.f, 0.f, 0.f, 0.f};
    float4 a1 = {0.f, 0.f, 0.f, 0.f};
    float4 a2 = {0.f, 0.f, 0.f, 0.f};
    float4 a3 = {0.f, 0.f, 0.f, 0.f};
    int e = start;
    for (; e + 3 < end; e += 4) {
        int2 p0 = pairs[e];
        int2 p1 = pairs[e + 1];
        int2 p2 = pairs[e + 2];
        int2 p3 = pairs[e + 3];
        float4 x0 = x4[(size_t)p0.x * cs];
        float4 x1 = x4[(size_t)p1.x * cs];
        float4 x2 = x4[(size_t)p2.x * cs];
        float4 x3 = x4[(size_t)p3.x * cs];
        float v0 = __int_as_float(p0.y);
        float v1 = __int_as_float(p1.y);
        float v2 = __int_as_float(p2.y);
        float v3 = __int_as_float(p3.y);
        a0.x += v0 * x0.x; a0.y += v0 * x0.y; a0.z += v0 * x0.z; a0.w += v0 * x0.w;
        a1.x += v1 * x1.x; a1.y += v1 * x1.y; a1.z += v1 * x1.z; a1.w += v1 * x1.w;
        a2.x += v2 * x2.x; a2.y += v2 * x2.y; a2.z += v2 * x2.z; a2.w += v2 * x2.w;
        a3.x += v3 * x3.x; a3.y += v3 * x3.y; a3.z += v3 * x3.z; a3.w += v3 * x3.w;
    }
    for (; e < end; ++e) {
        int2 p0 = pairs[e];
        float4 x0 = x4[(size_t)p0.x * cs];
        float v0 = __int_as_float(p0.y);
        a0.x += v0 * x0.x; a0.y += v0 * x0.y; a0.z += v0 * x0.z; a0.w += v0 * x0.w;
    }
    float4 acc;
    acc.x = (a0.x + a1.x) + (a2.x + a3.x);
    acc.y = (a0.y + a1.y) + (a2.y + a3.y);
    acc.z = (a0.z + a1.z) + (a2.z + a3.z);
    acc.w = (a0.w + a1.w) + (a2.w + a3.w);
    if (ABS) {
        acc.x = fabsf(acc.x); acc.y = fabsf(acc.y);
        acc.z = fabsf(acc.z); acc.w = fabsf(acc.w);
    }
    ((float4*)ys)[(size_t)s * N4F + (size_t)r * 4 + sub] = acc;
}

// ===========================================================================
// Attention: e[n,b] = dot(relu(pair_b[n]), a); att = softmax over b (6).
// B is slice-major [6][8][N][16]; X standard.
// ===========================================================================
__global__ __launch_bounds__(256) void attn_kernel(
    const float* __restrict__ X, const float* __restrict__ B,
    const float* __restrict__ a, float* __restrict__ att)
{
    int wid  = (blockIdx.x * 256 + threadIdx.x) >> 6;
    int lane = threadIdx.x & 63;
    if (wid >= N_NODES) return;

    const float4 av = ((const float4*)a)[lane];
    float e[6];

    if (wid < N_NODES / 2) {
        const float4 p = ((const float4*)(X + (size_t)wid * 256))[lane];
        float s = fmaxf(p.x, 0.f) * av.x + fmaxf(p.y, 0.f) * av.y +
                  fmaxf(p.z, 0.f) * av.z + fmaxf(p.w, 0.f) * av.w;
        #pragma unroll
        for (int m = 1; m < 64; m <<= 1) s += __shfl_xor(s, m);
        #pragma unroll
        for (int b = 0; b < 6; ++b) e[b] = s;
    } else {
        int m   = 2 * wid - N_NODES;
        int row = m + (lane >> 5);      // rows m, m+1
        int q   = lane & 31;            // float4 idx within row
        size_t o4 = (size_t)(q >> 2) * N4F + (size_t)row * 4 + (q & 3);
        #pragma unroll
        for (int b = 0; b < 6; ++b) {
            const float4 p = ((const float4*)(B + (size_t)b * NH))[o4];
            float s = fmaxf(p.x, 0.f) * av.x + fmaxf(p.y, 0.f) * av.y +
                      fmaxf(p.z, 0.f) * av.z + fmaxf(p.w, 0.f) * av.w;
            #pragma unroll
            for (int k = 1; k < 64; k <<= 1) s += __shfl_xor(s, k);
            e[b] = s;
        }
    }

    if (lane == 0) {
        float mx = e[0];
        #pragma unroll
        for (int b = 1; b < 6; ++b) mx = fmaxf(mx, e[b]);
        float ex[6], sum = 0.f;
        #pragma unroll
        for (int b = 0; b < 6; ++b) { ex[b] = expf(e[b] - mx); sum += ex[b]; }
        float inv = 1.f / sum;
        #pragma unroll
        for (int b = 0; b < 6; ++b) att[(size_t)wid * 6 + b] = ex[b] * inv;
    }
}

// ===========================================================================
// h_prime[n,q] = (1/6) * sum_p att[n,p] * B_{(p*128+q)%6}[n, (p*128+q)/6]
// B slice-major; hp standard (feeds fc_tile).
// ===========================================================================
__global__ __launch_bounds__(256) void hprime_kernel(
    const float* __restrict__ B, const float* __restrict__ att,
    float* __restrict__ hp)
{
    int idx = blockIdx.x * 256 + threadIdx.x;
    if (idx >= NH) return;
    int n = idx >> 7;
    int q = idx & 127;
    float s = 0.f;
    #pragma unroll
    for (int p = 0; p < 6; ++p) {
        int f  = p * HID + q;
        int jj = f % 6;
        int ii = f / 6;
        s += att[(size_t)n * 6 + p] *
             B[(size_t)jj * NH + (size_t)(ii >> 4) * (N_NODES * 16) +
               (size_t)n * 16 + (ii & 15)];
    }
    hp[idx] = s * (1.0f / 6.0f);
}

// ===========================================================================
// Register-tiled FC: out[n,o] = leaky_relu(dot(in[n,:], W[o,:]) + b[o])
// ===========================================================================
__global__ __launch_bounds__(256) void fc_tile_kernel(
    const float* __restrict__ in, const float* __restrict__ W,
    const float* __restrict__ bias, float* __restrict__ out)
{
    __shared__ float xs[128][33];
    __shared__ float wsm[128][33];
    const int t  = threadIdx.x;
    const int tr = t >> 4;
    const int tc = t & 15;
    const int n0 = blockIdx.x * 128;

    float acc[8][8];
    #pragma unroll
    for (int i = 0; i < 8; ++i)
        #pragma unroll
        for (int j = 0; j < 8; ++j) acc[i][j] = 0.f;

    for (int kc = 0; kc < 4; ++kc) {
        __syncthreads();
        #pragma unroll
        for (int q = 0; q < 4; ++q) {
            int f4  = q * 256 + t;
            int row = f4 >> 3;
            int kq  = f4 & 7;
            int n   = min(n0 + row, N_NODES - 1);
            float4 v = ((const float4*)in)[(size_t)n * 32 + kc * 8 + kq];
            xs[row][kq * 4 + 0] = v.x;
            xs[row][kq * 4 + 1] = v.y;
            xs[row][kq * 4 + 2] = v.z;
            xs[row][kq * 4 + 3] = v.w;
            float4 w = ((const float4*)W)[(size_t)row * 32 + kc * 8 + kq];
            wsm[row][kq * 4 + 0] = w.x;
            wsm[row][kq * 4 + 1] = w.y;
            wsm[row][kq * 4 + 2] = w.z;
            wsm[row][kq * 4 + 3] = w.w;
        }
        __syncthreads();
        #pragma unroll
        for (int k = 0; k < 32; ++k) {
            float xv[8], wv[8];
            #pragma unroll
            for (int i = 0; i < 8; ++i) xv[i] = xs[tr + 16 * i][k];
            #pragma unroll
            for (int j = 0; j < 8; ++j) wv[j] = wsm[tc + 16 * j][k];
            #pragma unroll
            for (int i = 0; i < 8; ++i)
                #pragma unroll
                for (int j = 0; j < 8; ++j)
                    acc[i][j] += xv[i] * wv[j];
        }
    }

    #pragma unroll
    for (int j = 0; j < 8; ++j) {
        int o = tc + 16 * j;
        float bo = bias[o];
        #pragma unroll
        for (int i = 0; i < 8; ++i) {
            int n = n0 + tr + 16 * i;
            if (n < N_NODES) {
                float v = acc[i][j] + bo;
                v = v > 0.f ? v : 0.01f * v;
                out[(size_t)n * HID + o] = v;
            }
        }
    }
}

// ===========================================================================
extern "C" void kernel_launch(void* const* d_in, const int* in_sizes, int n_in,
                              void* d_out, int out_size, void* d_ws, size_t ws_size,
                              hipStream_t stream)
{
    const float* X  = (const float*)d_in[0];
    const float* a  = (const float*)d_in[1];
    const float* W1 = (const float*)d_in[2];
    const float* b1 = (const float*)d_in[3];
    const float* W2 = (const float*)d_in[4];
    const float* b2 = (const float*)d_in[5];
    const int*   op_rows[4] = { (const int*)d_in[6],  (const int*)d_in[9],
                                (const int*)d_in[12], (const int*)d_in[15] };
    const int*   op_cols[4] = { (const int*)d_in[7],  (const int*)d_in[10],
                                (const int*)d_in[13], (const int*)d_in[16] };
    const float* op_vals[4] = { (const float*)d_in[8],  (const float*)d_in[11],
                                (const float*)d_in[14], (const float*)d_in[17] };
    // d_in[18..20] = Psct (unused: withgres=False)

    // ---- workspace layout (4-byte words) ----
    const size_t need_with_xs =
        ((size_t)6 * NH + 6 * N_NODES + NH + (N_NODES + 2) + (TBL + 1) + 1024 +
         NE / 2 + (size_t)4 * NE) * 4;
    const bool useXs = ws_size >= need_with_xs;

    float* ws = (float*)d_ws;
    size_t off = 0;
    float* B   = ws;                 off += (size_t)6 * NH;
    float* att = ws + off;           off += (size_t)6 * N_NODES;
    float* Xs  = ws + off;           if (useXs) off += NH;
    int*   ptr   = (int*)(ws + off); off += N_NODES + 2;
    int*   table = (int*)(ws + off); off += TBL + 1;
    int*   part  = (int*)(ws + off); off += 1024;
    unsigned short* brnk = (unsigned short*)(ws + off); off += NE / 2;
    int2*  tmp   = (int2*)(ws + off); off += (size_t)2 * NE;
    int2*  pairs = (int2*)(ws + off);
    float* mid   = (float*)tmp;      // aliases tmp (dead after last sort)

    float* hp = (float*)d_out;       // hprime output lives in d_out

    dim3 blk(256);
    const int sg = RBS * 8;                    // 6256 sliced-spmm blocks
    const int fg = (N_NODES + 127) / 128;      // 391

    auto sort_op = [&](int o) {
        k1_hist<<<NBLK1, blk, 0, stream>>>(op_rows[o], table, brnk);
        s1_partial<<<SB, blk, 0, stream>>>(table, part);
        s2_scan<<<1, 1024, 0, stream>>>(part);
        s3_add<<<SB, blk, 0, stream>>>(table, part);
        k3_scatter<<<NBLK1, blk, 0, stream>>>(op_rows[o], op_cols[o], op_vals[o],
                                              brnk, table, tmp);
        k4_fine<<<NBUK, blk, 0, stream>>>(table, tmp, pairs, ptr);
    };

    // first-hop source: slice-major Xs if ws allows, else standard X
    const float* x0 = useXs ? (const float*)Xs : X;
    if (useXs)
        to_slices_kernel<<<(N_NODES * 32) / 256, blk, 0, stream>>>(X, Xs);

    // ---- A: sort, then 3 chained hops (all outputs slice-major) ----
    sort_op(0);
    if (useXs)
        csr_spmm_kernel<false, false><<<sg, blk, 0, stream>>>(ptr, pairs, x0, B + 0 * (size_t)NH);
    else
        csr_spmm_kernel<false, true ><<<sg, blk, 0, stream>>>(ptr, pairs, x0, B + 0 * (size_t)NH);
    csr_spmm_kernel<false, false><<<sg, blk, 0, stream>>>(ptr, pairs, B + 0 * (size_t)NH, B + 1 * (size_t)NH);
    csr_spmm_kernel<false, false><<<sg, blk, 0, stream>>>(ptr, pairs, B + 1 * (size_t)NH, B + 2 * (size_t)NH);

    // ---- P1..P3: sort (reusing buffers), spmm with fused abs ----
    for (int i = 0; i < 3; ++i) {
        sort_op(1 + i);
        if (useXs)
            csr_spmm_kernel<true, false><<<sg, blk, 0, stream>>>(ptr, pairs, x0, B + (size_t)(3 + i) * NH);
        else
            csr_spmm_kernel<true, true ><<<sg, blk, 0, stream>>>(ptr, pairs, x0, B + (size_t)(3 + i) * NH);
    }

    // ---- attention, hprime, register-tiled FCs ----
    attn_kernel<<<(N_NODES + 3) / 4, blk, 0, stream>>>(X, B, a, att);
    hprime_kernel<<<(NH + 255) / 256, blk, 0, stream>>>(B, att, hp);
    fc_tile_kernel<<<fg, blk, 0, stream>>>(hp,  W1, b1, mid);
    fc_tile_kernel<<<fg, blk, 0, stream>>>(mid, W2, b2, (float*)d_out);
}

// Round 10
// 871.861 us; speedup vs baseline: 1.3129x; 1.3129x over previous
//
#include <hip/hip_runtime.h>
#include <hip/hip_fp16.h>

#define N_NODES 50000
#define HID 128
#define NE 1600000
#define NH (N_NODES * HID)      // 6,400,000 elems per [N,HID] buffer

#define EPB   4096              // edges per K1/K3 block
#define NBLK1 391               // ceil(NE / EPB)
#define NBUK  391               // ceil(N_NODES / 128) row buckets (128 rows each)
#define TBL   (NBUK * NBLK1)    // 152,881 scan table entries
#define SB    ((TBL + 255) / 256)  // 598 scan blocks

// ---- fp16 helpers (RNE) ----
__device__ __forceinline__ float h2f(unsigned short u) {
    __half_raw r; r.x = u;
    __half h = r;
    return __half2float(h);
}
__device__ __forceinline__ unsigned short f2h(float f) {
    __half h = __float2half_rn(f);
    __half_raw r = h;
    return r.x;
}

// ===========================================================================
// K1: per-block LDS histogram over 391 coarse buckets + per-edge rank.
// ===========================================================================
__global__ __launch_bounds__(256) void k1_hist(
    const int* __restrict__ rows, int* __restrict__ table,
    unsigned short* __restrict__ rank)
{
    __shared__ int h[NBUK];
    int b = blockIdx.x, t = threadIdx.x;
    for (int i = t; i < NBUK; i += 256) h[i] = 0;
    __syncthreads();
    int e0 = b * EPB;
    int e1 = min(e0 + EPB, NE);
    for (int e = e0 + t; e < e1; e += 256)
        rank[e] = (unsigned short)atomicAdd(&h[rows[e] >> 7], 1);
    __syncthreads();
    for (int i = t; i < NBUK; i += 256) table[i * NBLK1 + b] = h[i];
}

// ===========================================================================
// S1/S2/S3: hierarchical exclusive scan of table[TBL]
// ===========================================================================
__global__ __launch_bounds__(256) void s1_partial(
    const int* __restrict__ table, int* __restrict__ part)
{
    __shared__ int red[256];
    int b = blockIdx.x, t = threadIdx.x;
    int idx = b * 256 + t;
    red[t] = (idx < TBL) ? table[idx] : 0;
    __syncthreads();
    #pragma unroll
    for (int s = 128; s > 0; s >>= 1) {
        if (t < s) red[t] += red[t + s];
        __syncthreads();
    }
    if (t == 0) part[b] = red[0];
}

__global__ __launch_bounds__(1024) void s2_scan(int* __restrict__ part)
{
    __shared__ int sh[1024];
    int t = threadIdx.x;
    sh[t] = (t < SB) ? part[t] : 0;
    __syncthreads();
    for (int off = 1; off < 1024; off <<= 1) {
        int v = (t >= off) ? sh[t - off] : 0;
        __syncthreads();
        sh[t] += v;
        __syncthreads();
    }
    if (t < SB) part[t] = (t == 0) ? 0 : sh[t - 1];
}

__global__ __launch_bounds__(256) void s3_add(
    int* __restrict__ table, const int* __restrict__ part)
{
    __shared__ int sh[256];
    int b = blockIdx.x, t = threadIdx.x;
    int idx = b * 256 + t;
    int v = (idx < TBL) ? table[idx] : 0;
    sh[t] = v;
    __syncthreads();
    #pragma unroll
    for (int off = 1; off < 256; off <<= 1) {
        int u = (t >= off) ? sh[t - off] : 0;
        __syncthreads();
        sh[t] += u;
        __syncthreads();
    }
    int excl = (t == 0) ? 0 : sh[t - 1];
    if (idx < TBL) table[idx] = part[b] + excl;
}

// ===========================================================================
// K3: atomic-free scatter into bucket-partitioned tmp.
// ===========================================================================
__global__ __launch_bounds__(256) void k3_scatter(
    const int* __restrict__ rows, const int* __restrict__ cols,
    const float* __restrict__ vals, const unsigned short* __restrict__ rank,
    const int* __restrict__ table, int2* __restrict__ tmp)
{
    __shared__ int base[NBUK];
    int b = blockIdx.x, t = threadIdx.x;
    for (int i = t; i < NBUK; i += 256) base[i] = table[i * NBLK1 + b];
    __syncthreads();
    int e0 = b * EPB;
    int e1 = min(e0 + EPB, NE);
    for (int e = e0 + t; e < e1; e += 256) {
        int r = rows[e];
        int pos = base[r >> 7] + (int)rank[e];
        tmp[pos] = make_int2(((r & 127) << 16) | cols[e], __float_as_int(vals[e]));
    }
}

// ===========================================================================
// K4: per-bucket fine sort -> final CSR pairs + rowptr.
// ===========================================================================
__global__ __launch_bounds__(256) void k4_fine(
    const int* __restrict__ table, const int2* __restrict__ tmp,
    int2* __restrict__ pairs, int* __restrict__ rowptr)
{
    __shared__ int cnt[128];
    __shared__ int sh[256];
    __shared__ int nxt[128];
    int k = blockIdx.x, t = threadIdx.x;
    if (t < 128) cnt[t] = 0;
    __syncthreads();
    int base = table[k * NBLK1];
    int end  = (k == NBUK - 1) ? NE : table[(k + 1) * NBLK1];
    for (int e = base + t; e < end; e += 256)
        atomicAdd(&cnt[(tmp[e].x >> 16) & 127], 1);
    __syncthreads();
    sh[t] = (t < 128) ? cnt[t] : 0;
    __syncthreads();
    #pragma unroll
    for (int off = 1; off < 256; off <<= 1) {
        int v = (t >= off) ? sh[t - off] : 0;
        __syncthreads();
        sh[t] += v;
        __syncthreads();
    }
    if (t < 128) {
        int excl = (t == 0) ? 0 : sh[t - 1];
        nxt[t] = base + excl;
        int row = k * 128 + t;
        if (row < N_NODES) rowptr[row] = base + excl;
    }
    if (k == NBUK - 1 && t == 255) rowptr[N_NODES] = NE;
    __syncthreads();
    for (int e = base + t; e < end; e += 256) {
        int2 p = tmp[e];
        int pos = atomicAdd(&nxt[(p.x >> 16) & 127], 1);
        pairs[pos] = make_int2(p.x & 0xFFFF, p.y);
    }
}

// ===========================================================================
// cvt: fp32 [N][128] -> fp16 [N][128] (RNE)
// ===========================================================================
__global__ __launch_bounds__(256) void cvt_f2h_kernel(
    const float* __restrict__ in, unsigned short* __restrict__ out)
{
    int i = blockIdx.x * 256 + threadIdx.x;     // float4 id
    if (i >= NH / 4) return;
    float4 v = ((const float4*)in)[i];
    ushort4 o;
    o.x = f2h(v.x); o.y = f2h(v.y); o.z = f2h(v.z); o.w = f2h(v.w);
    ((ushort4*)out)[i] = o;
}

// ===========================================================================
// CSR SpMM with fp16 gather source, fp32 accumulate + fp32 store.
// 32 lanes per row, each lane owns 4 cols (one ushort4 = 8B); 4-way unroll.
// Per edge: 32 lanes x 8B = 256B = 4 cache lines (vs 8 for fp32).
// ===========================================================================
template <bool ABS>
__global__ __launch_bounds__(256) void spmm_h_kernel(
    const int* __restrict__ rowptr, const int2* __restrict__ pairs,
    const unsigned short* __restrict__ xh, float* __restrict__ y)
{
    int t   = blockIdx.x * 256 + threadIdx.x;
    int r   = t >> 5;
    int sub = t & 31;
    if (r >= N_NODES) return;

    const ushort4* x4 = (const ushort4*)xh + sub;  // row stride = 32 ushort4
    int start = rowptr[r], end = rowptr[r + 1];

    float4 a0 = {0,0,0,0}, a1 = {0,0,0,0};
    float4 a2 = {0,0,0,0}, a3 = {0,0,0,0};

    #define EDGE_H(P, A) { \
        ushort4 _x = x4[(size_t)(P).x * 32]; \
        float _v = __int_as_float((P).y); \
        A.x += _v * h2f(_x.x); \
        A.y += _v * h2f(_x.y); \
        A.z += _v * h2f(_x.z); \
        A.w += _v * h2f(_x.w); }

    int e = start;
    for (; e + 3 < end; e += 4) {
        int2 p0 = pairs[e];
        int2 p1 = pairs[e + 1];
        int2 p2 = pairs[e + 2];
        int2 p3 = pairs[e + 3];
        EDGE_H(p0, a0); EDGE_H(p1, a1); EDGE_H(p2, a2); EDGE_H(p3, a3);
    }
    for (; e < end; ++e) {
        int2 p0 = pairs[e];
        EDGE_H(p0, a0);
    }
    #undef EDGE_H

    float4 acc;
    acc.x = (a0.x + a1.x) + (a2.x + a3.x);
    acc.y = (a0.y + a1.y) + (a2.y + a3.y);
    acc.z = (a0.z + a1.z) + (a2.z + a3.z);
    acc.w = (a0.w + a1.w) + (a2.w + a3.w);
    if (ABS) {
        acc.x = fabsf(acc.x); acc.y = fabsf(acc.y);
        acc.z = fabsf(acc.z); acc.w = fabsf(acc.w);
    }
    ((float4*)(y + (size_t)r * HID))[sub] = acc;
}

// ===========================================================================
// Attention: e[n,b] = dot(relu(pair_b[n]), a); att = softmax over b (6)
// (standard [N][128] fp32 branches)
// ===========================================================================
__global__ __launch_bounds__(256) void attn_kernel(
    const float* __restrict__ X, const float* __restrict__ B,
    const float* __restrict__ a, float* __restrict__ att)
{
    int wid  = (blockIdx.x * 256 + threadIdx.x) >> 6;
    int lane = threadIdx.x & 63;
    if (wid >= N_NODES) return;

    const float4 av = ((const float4*)a)[lane];
    float e[6];

    if (wid < N_NODES / 2) {
        const float4 p = ((const float4*)(X + (size_t)wid * 256))[lane];
        float s = fmaxf(p.x, 0.f) * av.x + fmaxf(p.y, 0.f) * av.y +
                  fmaxf(p.z, 0.f) * av.z + fmaxf(p.w, 0.f) * av.w;
        #pragma unroll
        for (int m = 1; m < 64; m <<= 1) s += __shfl_xor(s, m);
        #pragma unroll
        for (int b = 0; b < 6; ++b) e[b] = s;
    } else {
        int m = 2 * wid - N_NODES;
        #pragma unroll
        for (int b = 0; b < 6; ++b) {
            const float4 p =
                ((const float4*)(B + (size_t)b * NH + (size_t)m * HID))[lane];
            float s = fmaxf(p.x, 0.f) * av.x + fmaxf(p.y, 0.f) * av.y +
                      fmaxf(p.z, 0.f) * av.z + fmaxf(p.w, 0.f) * av.w;
            #pragma unroll
            for (int k = 1; k < 64; k <<= 1) s += __shfl_xor(s, k);
            e[b] = s;
        }
    }

    if (lane == 0) {
        float mx = e[0];
        #pragma unroll
        for (int b = 1; b < 6; ++b) mx = fmaxf(mx, e[b]);
        float ex[6], sum = 0.f;
        #pragma unroll
        for (int b = 0; b < 6; ++b) { ex[b] = expf(e[b] - mx); sum += ex[b]; }
        float inv = 1.f / sum;
        #pragma unroll
        for (int b = 0; b < 6; ++b) att[(size_t)wid * 6 + b] = ex[b] * inv;
    }
}

// ===========================================================================
// h_prime[n,q] = (1/6) * sum_p att[n,p] * B_{(p*128+q)%6}[n, (p*128+q)/6]
// ===========================================================================
__global__ __launch_bounds__(256) void hprime_kernel(
    const float* __restrict__ B, const float* __restrict__ att,
    float* __restrict__ hp)
{
    int idx = blockIdx.x * 256 + threadIdx.x;
    if (idx >= NH) return;
    int n = idx >> 7;
    int q = idx & 127;
    float s = 0.f;
    #pragma unroll
    for (int p = 0; p < 6; ++p) {
        int f = p * HID + q;
        int j = f % 6;
        int i = f / 6;
        s += att[(size_t)n * 6 + p] * B[(size_t)j * NH + (size_t)n * HID + i];
    }
    hp[idx] = s * (1.0f / 6.0f);
}

// ===========================================================================
// Register-tiled FC: out[n,o] = leaky_relu(dot(in[n,:], W[o,:]) + b[o])
// ===========================================================================
__global__ __launch_bounds__(256) void fc_tile_kernel(
    const float* __restrict__ in, const float* __restrict__ W,
    const float* __restrict__ bias, float* __restrict__ out)
{
    __shared__ float xs[128][33];
    __shared__ float wsm[128][33];
    const int t  = threadIdx.x;
    const int tr = t >> 4;
    const int tc = t & 15;
    const int n0 = blockIdx.x * 128;

    float acc[8][8];
    #pragma unroll
    for (int i = 0; i < 8; ++i)
        #pragma unroll
        for (int j = 0; j < 8; ++j) acc[i][j] = 0.f;

    for (int kc = 0; kc < 4; ++kc) {
        __syncthreads();
        #pragma unroll
        for (int q = 0; q < 4; ++q) {
            int f4  = q * 256 + t;
            int row = f4 >> 3;
            int kq  = f4 & 7;
            int n   = min(n0 + row, N_NODES - 1);
            float4 v = ((const float4*)in)[(size_t)n * 32 + kc * 8 + kq];
            xs[row][kq * 4 + 0] = v.x;
            xs[row][kq * 4 + 1] = v.y;
            xs[row][kq * 4 + 2] = v.z;
            xs[row][kq * 4 + 3] = v.w;
            float4 w = ((const float4*)W)[(size_t)row * 32 + kc * 8 + kq];
            wsm[row][kq * 4 + 0] = w.x;
            wsm[row][kq * 4 + 1] = w.y;
            wsm[row][kq * 4 + 2] = w.z;
            wsm[row][kq * 4 + 3] = w.w;
        }
        __syncthreads();
        #pragma unroll
        for (int k = 0; k < 32; ++k) {
            float xv[8], wv[8];
            #pragma unroll
            for (int i = 0; i < 8; ++i) xv[i] = xs[tr + 16 * i][k];
            #pragma unroll
            for (int j = 0; j < 8; ++j) wv[j] = wsm[tc + 16 * j][k];
            #pragma unroll
            for (int i = 0; i < 8; ++i)
                #pragma unroll
                for (int j = 0; j < 8; ++j)
                    acc[i][j] += xv[i] * wv[j];
        }
    }

    #pragma unroll
    for (int j = 0; j < 8; ++j) {
        int o = tc + 16 * j;
        float bo = bias[o];
        #pragma unroll
        for (int i = 0; i < 8; ++i) {
            int n = n0 + tr + 16 * i;
            if (n < N_NODES) {
                float v = acc[i][j] + bo;
                v = v > 0.f ? v : 0.01f * v;
                out[(size_t)n * HID + o] = v;
            }
        }
    }
}

// ===========================================================================
extern "C" void kernel_launch(void* const* d_in, const int* in_sizes, int n_in,
                              void* d_out, int out_size, void* d_ws, size_t ws_size,
                              hipStream_t stream)
{
    const float* X  = (const float*)d_in[0];
    const float* a  = (const float*)d_in[1];
    const float* W1 = (const float*)d_in[2];
    const float* b1 = (const float*)d_in[3];
    const float* W2 = (const float*)d_in[4];
    const float* b2 = (const float*)d_in[5];
    const int*   op_rows[4] = { (const int*)d_in[6],  (const int*)d_in[9],
                                (const int*)d_in[12], (const int*)d_in[15] };
    const int*   op_cols[4] = { (const int*)d_in[7],  (const int*)d_in[10],
                                (const int*)d_in[13], (const int*)d_in[16] };
    const float* op_vals[4] = { (const float*)d_in[8],  (const float*)d_in[11],
                                (const float*)d_in[14], (const float*)d_in[17] };
    // d_in[18..20] = Psct (unused: withgres=False)

    // ---- workspace layout (4-byte words) ----
    float* ws = (float*)d_ws;
    size_t off = 0;
    float* B   = ws;                                    off += (size_t)6 * NH;   // 6 fp32 branches [N][128]
    float* att = ws + off;                              off += (size_t)6 * N_NODES;
    unsigned short* Xh = (unsigned short*)(ws + off);   off += NH / 2;           // X fp16 [N][128]
    int*   ptr   = (int*)(ws + off);                    off += N_NODES + 2;
    int*   table = (int*)(ws + off);                    off += TBL + 1;
    int*   part  = (int*)(ws + off);                    off += 1024;
    unsigned short* brnk = (unsigned short*)(ws + off); off += NE / 2;
    if (off & 1) off++;                                 // 8B align
    int2*  tmp   = (int2*)(ws + off);                   off += (size_t)2 * NE;
    int2*  pairs = (int2*)(ws + off);                   off += (size_t)2 * NE;
    // hh (fp16 chain source) aliases tmp: tmp is dead between sort_op(0) and
    // sort_op(1); all chain hops run in that window. mid (fc intermediate)
    // also aliases tmp: dead after the last sort.
    unsigned short* hh = (unsigned short*)tmp;
    float* mid = (float*)tmp;

    float* hp = (float*)d_out;    // hprime output lives in d_out

    dim3 blk(256);
    const int rg = (N_NODES * 32 + 255) / 256;  // 6250
    const int cg = (NH / 4 + 255) / 256;        // 6250
    const int fg = (N_NODES + 127) / 128;       // 391

    auto sort_op = [&](int o) {
        k1_hist<<<NBLK1, blk, 0, stream>>>(op_rows[o], table, brnk);
        s1_partial<<<SB, blk, 0, stream>>>(table, part);
        s2_scan<<<1, 1024, 0, stream>>>(part);
        s3_add<<<SB, blk, 0, stream>>>(table, part);
        k3_scatter<<<NBLK1, blk, 0, stream>>>(op_rows[o], op_cols[o], op_vals[o],
                                              brnk, table, tmp);
        k4_fine<<<NBUK, blk, 0, stream>>>(table, tmp, pairs, ptr);
    };

    cvt_f2h_kernel<<<cg, blk, 0, stream>>>(X, Xh);

    // ---- A chain: all hops gather fp16, store fp32 ----
    sort_op(0);
    spmm_h_kernel<false><<<rg, blk, 0, stream>>>(ptr, pairs, Xh, B + 0 * (size_t)NH);
    cvt_f2h_kernel<<<cg, blk, 0, stream>>>(B + 0 * (size_t)NH, hh);
    spmm_h_kernel<false><<<rg, blk, 0, stream>>>(ptr, pairs, hh, B + 1 * (size_t)NH);
    cvt_f2h_kernel<<<cg, blk, 0, stream>>>(B + 1 * (size_t)NH, hh);
    spmm_h_kernel<false><<<rg, blk, 0, stream>>>(ptr, pairs, hh, B + 2 * (size_t)NH);

    // ---- P1..P3: fp16 gather of X, fp32 store, fused abs ----
    for (int i = 0; i < 3; ++i) {
        sort_op(1 + i);
        spmm_h_kernel<true><<<rg, blk, 0, stream>>>(ptr, pairs, Xh,
                                                    B + (size_t)(3 + i) * NH);
    }

    // ---- attention, hprime, register-tiled FCs ----
    attn_kernel<<<(N_NODES + 3) / 4, blk, 0, stream>>>(X, B, a, att);
    hprime_kernel<<<(NH + 255) / 256, blk, 0, stream>>>(B, att, hp);
    fc_tile_kernel<<<fg, blk, 0, stream>>>(hp,  W1, b1, mid);
    fc_tile_kernel<<<fg, blk, 0, stream>>>(mid, W2, b2, (float*)d_out);
}

// Round 11
// 862.475 us; speedup vs baseline: 1.3272x; 1.0109x over previous
//
#include <hip/hip_runtime.h>
#include <hip/hip_fp16.h>

#define N_NODES 50000
#define HID 128
#define NE 1600000
#define NH (N_NODES * HID)      // 6,400,000 elems per [N,HID] buffer

#define EPB   4096              // edges per K1/K3 block
#define NBLK1 391               // ceil(NE / EPB)
#define NBUK  391               // ceil(N_NODES / 128) row buckets (128 rows each)
#define TBL   (NBUK * NBLK1)    // 152,881 scan table entries
#define SB    ((TBL + 255) / 256)  // 598 scan blocks

// ---- fp16 helpers (RNE) ----
__device__ __forceinline__ float h2f(unsigned short u) {
    __half_raw r; r.x = u;
    __half h = r;
    return __half2float(h);
}
__device__ __forceinline__ unsigned short f2h(float f) {
    __half h = __float2half_rn(f);
    __half_raw r = h;
    return r.x;
}

// ===========================================================================
// K1: per-block LDS histogram over 391 coarse buckets + per-edge rank.
// ===========================================================================
__global__ __launch_bounds__(256) void k1_hist(
    const int* __restrict__ rows, int* __restrict__ table,
    unsigned short* __restrict__ rank)
{
    __shared__ int h[NBUK];
    int b = blockIdx.x, t = threadIdx.x;
    for (int i = t; i < NBUK; i += 256) h[i] = 0;
    __syncthreads();
    int e0 = b * EPB;
    int e1 = min(e0 + EPB, NE);
    for (int e = e0 + t; e < e1; e += 256)
        rank[e] = (unsigned short)atomicAdd(&h[rows[e] >> 7], 1);
    __syncthreads();
    for (int i = t; i < NBUK; i += 256) table[i * NBLK1 + b] = h[i];
}

// ===========================================================================
// S1/S2/S3: hierarchical exclusive scan of table[TBL]
// ===========================================================================
__global__ __launch_bounds__(256) void s1_partial(
    const int* __restrict__ table, int* __restrict__ part)
{
    __shared__ int red[256];
    int b = blockIdx.x, t = threadIdx.x;
    int idx = b * 256 + t;
    red[t] = (idx < TBL) ? table[idx] : 0;
    __syncthreads();
    #pragma unroll
    for (int s = 128; s > 0; s >>= 1) {
        if (t < s) red[t] += red[t + s];
        __syncthreads();
    }
    if (t == 0) part[b] = red[0];
}

__global__ __launch_bounds__(1024) void s2_scan(int* __restrict__ part)
{
    __shared__ int sh[1024];
    int t = threadIdx.x;
    sh[t] = (t < SB) ? part[t] : 0;
    __syncthreads();
    for (int off = 1; off < 1024; off <<= 1) {
        int v = (t >= off) ? sh[t - off] : 0;
        __syncthreads();
        sh[t] += v;
        __syncthreads();
    }
    if (t < SB) part[t] = (t == 0) ? 0 : sh[t - 1];
}

__global__ __launch_bounds__(256) void s3_add(
    int* __restrict__ table, const int* __restrict__ part)
{
    __shared__ int sh[256];
    int b = blockIdx.x, t = threadIdx.x;
    int idx = b * 256 + t;
    int v = (idx < TBL) ? table[idx] : 0;
    sh[t] = v;
    __syncthreads();
    #pragma unroll
    for (int off = 1; off < 256; off <<= 1) {
        int u = (t >= off) ? sh[t - off] : 0;
        __syncthreads();
        sh[t] += u;
        __syncthreads();
    }
    int excl = (t == 0) ? 0 : sh[t - 1];
    if (idx < TBL) table[idx] = part[b] + excl;
}

// ===========================================================================
// K3: atomic-free scatter into bucket-partitioned tmp.
// ===========================================================================
__global__ __launch_bounds__(256) void k3_scatter(
    const int* __restrict__ rows, const int* __restrict__ cols,
    const float* __restrict__ vals, const unsigned short* __restrict__ rank,
    const int* __restrict__ table, int2* __restrict__ tmp)
{
    __shared__ int base[NBUK];
    int b = blockIdx.x, t = threadIdx.x;
    for (int i = t; i < NBUK; i += 256) base[i] = table[i * NBLK1 + b];
    __syncthreads();
    int e0 = b * EPB;
    int e1 = min(e0 + EPB, NE);
    for (int e = e0 + t; e < e1; e += 256) {
        int r = rows[e];
        int pos = base[r >> 7] + (int)rank[e];
        tmp[pos] = make_int2(((r & 127) << 16) | cols[e], __float_as_int(vals[e]));
    }
}

// ===========================================================================
// K4: per-bucket fine sort -> final CSR pairs + rowptr.
// ===========================================================================
__global__ __launch_bounds__(256) void k4_fine(
    const int* __restrict__ table, const int2* __restrict__ tmp,
    int2* __restrict__ pairs, int* __restrict__ rowptr)
{
    __shared__ int cnt[128];
    __shared__ int sh[256];
    __shared__ int nxt[128];
    int k = blockIdx.x, t = threadIdx.x;
    if (t < 128) cnt[t] = 0;
    __syncthreads();
    int base = table[k * NBLK1];
    int end  = (k == NBUK - 1) ? NE : table[(k + 1) * NBLK1];
    for (int e = base + t; e < end; e += 256)
        atomicAdd(&cnt[(tmp[e].x >> 16) & 127], 1);
    __syncthreads();
    sh[t] = (t < 128) ? cnt[t] : 0;
    __syncthreads();
    #pragma unroll
    for (int off = 1; off < 256; off <<= 1) {
        int v = (t >= off) ? sh[t - off] : 0;
        __syncthreads();
        sh[t] += v;
        __syncthreads();
    }
    if (t < 128) {
        int excl = (t == 0) ? 0 : sh[t - 1];
        nxt[t] = base + excl;
        int row = k * 128 + t;
        if (row < N_NODES) rowptr[row] = base + excl;
    }
    if (k == NBUK - 1 && t == 255) rowptr[N_NODES] = NE;
    __syncthreads();
    for (int e = base + t; e < end; e += 256) {
        int2 p = tmp[e];
        int pos = atomicAdd(&nxt[(p.x >> 16) & 127], 1);
        pairs[pos] = make_int2(p.x & 0xFFFF, p.y);
    }
}

// ===========================================================================
// cvt: fp32 [N][128] -> fp16 [N][128] (RNE)
// ===========================================================================
__global__ __launch_bounds__(256) void cvt_f2h_kernel(
    const float* __restrict__ in, unsigned short* __restrict__ out)
{
    int i = blockIdx.x * 256 + threadIdx.x;     // float4 id
    if (i >= NH / 4) return;
    float4 v = ((const float4*)in)[i];
    ushort4 o;
    o.x = f2h(v.x); o.y = f2h(v.y); o.z = f2h(v.z); o.w = f2h(v.w);
    ((ushort4*)out)[i] = o;
}

// ===========================================================================
// CSR SpMM with fp16 gather source, fp32 accumulate + fp32 store.
// 32 lanes per row, each lane owns 4 cols (one ushort4 = 8B); 4-way unroll.
// Per edge: 32 lanes x 8B = 256B = 4 cache lines (vs 8 for fp32).
// ===========================================================================
template <bool ABS>
__global__ __launch_bounds__(256) void spmm_h_kernel(
    const int* __restrict__ rowptr, const int2* __restrict__ pairs,
    const unsigned short* __restrict__ xh, float* __restrict__ y)
{
    int t   = blockIdx.x * 256 + threadIdx.x;
    int r   = t >> 5;
    int sub = t & 31;
    if (r >= N_NODES) return;

    const ushort4* x4 = (const ushort4*)xh + sub;  // row stride = 32 ushort4
    int start = rowptr[r], end = rowptr[r + 1];

    float4 a0 = {0,0,0,0}, a1 = {0,0,0,0};
    float4 a2 = {0,0,0,0}, a3 = {0,0,0,0};

    #define EDGE_H(P, A) { \
        ushort4 _x = x4[(size_t)(P).x * 32]; \
        float _v = __int_as_float((P).y); \
        A.x += _v * h2f(_x.x); \
        A.y += _v * h2f(_x.y); \
        A.z += _v * h2f(_x.z); \
        A.w += _v * h2f(_x.w); }

    int e = start;
    for (; e + 3 < end; e += 4) {
        int2 p0 = pairs[e];
        int2 p1 = pairs[e + 1];
        int2 p2 = pairs[e + 2];
        int2 p3 = pairs[e + 3];
        EDGE_H(p0, a0); EDGE_H(p1, a1); EDGE_H(p2, a2); EDGE_H(p3, a3);
    }
    for (; e < end; ++e) {
        int2 p0 = pairs[e];
        EDGE_H(p0, a0);
    }
    #undef EDGE_H

    float4 acc;
    acc.x = (a0.x + a1.x) + (a2.x + a3.x);
    acc.y = (a0.y + a1.y) + (a2.y + a3.y);
    acc.z = (a0.z + a1.z) + (a2.z + a3.z);
    acc.w = (a0.w + a1.w) + (a2.w + a3.w);
    if (ABS) {
        acc.x = fabsf(acc.x); acc.y = fabsf(acc.y);
        acc.z = fabsf(acc.z); acc.w = fabsf(acc.w);
    }
    ((float4*)(y + (size_t)r * HID))[sub] = acc;
}

// ===========================================================================
// Attention: e[n,b] = dot(relu(pair_b[n]), a); att = softmax over b (6)
// ===========================================================================
__global__ __launch_bounds__(256) void attn_kernel(
    const float* __restrict__ X, const float* __restrict__ B,
    const float* __restrict__ a, float* __restrict__ att)
{
    int wid  = (blockIdx.x * 256 + threadIdx.x) >> 6;
    int lane = threadIdx.x & 63;
    if (wid >= N_NODES) return;

    const float4 av = ((const float4*)a)[lane];
    float e[6];

    if (wid < N_NODES / 2) {
        const float4 p = ((const float4*)(X + (size_t)wid * 256))[lane];
        float s = fmaxf(p.x, 0.f) * av.x + fmaxf(p.y, 0.f) * av.y +
                  fmaxf(p.z, 0.f) * av.z + fmaxf(p.w, 0.f) * av.w;
        #pragma unroll
        for (int m = 1; m < 64; m <<= 1) s += __shfl_xor(s, m);
        #pragma unroll
        for (int b = 0; b < 6; ++b) e[b] = s;
    } else {
        int m = 2 * wid - N_NODES;
        #pragma unroll
        for (int b = 0; b < 6; ++b) {
            const float4 p =
                ((const float4*)(B + (size_t)b * NH + (size_t)m * HID))[lane];
            float s = fmaxf(p.x, 0.f) * av.x + fmaxf(p.y, 0.f) * av.y +
                      fmaxf(p.z, 0.f) * av.z + fmaxf(p.w, 0.f) * av.w;
            #pragma unroll
            for (int k = 1; k < 64; k <<= 1) s += __shfl_xor(s, k);
            e[b] = s;
        }
    }

    if (lane == 0) {
        float mx = e[0];
        #pragma unroll
        for (int b = 1; b < 6; ++b) mx = fmaxf(mx, e[b]);
        float ex[6], sum = 0.f;
        #pragma unroll
        for (int b = 0; b < 6; ++b) { ex[b] = expf(e[b] - mx); sum += ex[b]; }
        float inv = 1.f / sum;
        #pragma unroll
        for (int b = 0; b < 6; ++b) att[(size_t)wid * 6 + b] = ex[b] * inv;
    }
}

// ===========================================================================
// h_prime[n,q] = (1/6) * sum_p att[n,p] * B_{(p*128+q)%6}[n, (p*128+q)/6]
// ===========================================================================
__global__ __launch_bounds__(256) void hprime_kernel(
    const float* __restrict__ B, const float* __restrict__ att,
    float* __restrict__ hp)
{
    int idx = blockIdx.x * 256 + threadIdx.x;
    if (idx >= NH) return;
    int n = idx >> 7;
    int q = idx & 127;
    float s = 0.f;
    #pragma unroll
    for (int p = 0; p < 6; ++p) {
        int f = p * HID + q;
        int j = f % 6;
        int i = f / 6;
        s += att[(size_t)n * 6 + p] * B[(size_t)j * NH + (size_t)n * HID + i];
    }
    hp[idx] = s * (1.0f / 6.0f);
}

// ===========================================================================
// Register-tiled FC: out[n,o] = leaky_relu(dot(in[n,:], W[o,:]) + b[o])
// Block = 64 rows x 128 cols (782 blocks -> ~3 blocks/CU, latency fix);
// thread = 4x8 tile. LDS 25.3 KB -> 6 blocks/CU by LDS. Per k: 12 ds_read_b32
// feed 32 FMAs (64 cyc VALU vs 24 cyc LDS per wave -> VALU-dominated).
// ===========================================================================
__global__ __launch_bounds__(256) void fc_tile_kernel(
    const float* __restrict__ in, const float* __restrict__ W,
    const float* __restrict__ bias, float* __restrict__ out)
{
    __shared__ float xs[64][33];
    __shared__ float wsm[128][33];
    const int t  = threadIdx.x;
    const int tr = t >> 4;    // 0..15 (row group: rows tr + 16*i, i<4)
    const int tc = t & 15;    // 0..15 (col group: cols tc + 16*j, j<8)
    const int n0 = blockIdx.x * 64;

    float acc[4][8];
    #pragma unroll
    for (int i = 0; i < 4; ++i)
        #pragma unroll
        for (int j = 0; j < 8; ++j) acc[i][j] = 0.f;

    for (int kc = 0; kc < 4; ++kc) {
        __syncthreads();   // protect previous chunk's reads
        #pragma unroll
        for (int q = 0; q < 2; ++q) {          // x tile: 64 rows x 32 k
            int f4  = q * 256 + t;             // 0..511
            int row = f4 >> 3;                 // 0..63
            int kq  = f4 & 7;
            int n   = min(n0 + row, N_NODES - 1);
            float4 v = ((const float4*)in)[(size_t)n * 32 + kc * 8 + kq];
            xs[row][kq * 4 + 0] = v.x;
            xs[row][kq * 4 + 1] = v.y;
            xs[row][kq * 4 + 2] = v.z;
            xs[row][kq * 4 + 3] = v.w;
        }
        #pragma unroll
        for (int q = 0; q < 4; ++q) {          // W tile: 128 rows x 32 k
            int f4  = q * 256 + t;             // 0..1023
            int row = f4 >> 3;                 // 0..127
            int kq  = f4 & 7;
            float4 w = ((const float4*)W)[(size_t)row * 32 + kc * 8 + kq];
            wsm[row][kq * 4 + 0] = w.x;
            wsm[row][kq * 4 + 1] = w.y;
            wsm[row][kq * 4 + 2] = w.z;
            wsm[row][kq * 4 + 3] = w.w;
        }
        __syncthreads();
        #pragma unroll
        for (int k = 0; k < 32; ++k) {
            float xv[4], wv[8];
            #pragma unroll
            for (int i = 0; i < 4; ++i) xv[i] = xs[tr + 16 * i][k];
            #pragma unroll
            for (int j = 0; j < 8; ++j) wv[j] = wsm[tc + 16 * j][k];
            #pragma unroll
            for (int i = 0; i < 4; ++i)
                #pragma unroll
                for (int j = 0; j < 8; ++j)
                    acc[i][j] += xv[i] * wv[j];
        }
    }

    #pragma unroll
    for (int j = 0; j < 8; ++j) {
        int o = tc + 16 * j;
        float bo = bias[o];
        #pragma unroll
        for (int i = 0; i < 4; ++i) {
            int n = n0 + tr + 16 * i;
            if (n < N_NODES) {
                float v = acc[i][j] + bo;
                v = v > 0.f ? v : 0.01f * v;
                out[(size_t)n * HID + o] = v;
            }
        }
    }
}

// ===========================================================================
extern "C" void kernel_launch(void* const* d_in, const int* in_sizes, int n_in,
                              void* d_out, int out_size, void* d_ws, size_t ws_size,
                              hipStream_t stream)
{
    const float* X  = (const float*)d_in[0];
    const float* a  = (const float*)d_in[1];
    const float* W1 = (const float*)d_in[2];
    const float* b1 = (const float*)d_in[3];
    const float* W2 = (const float*)d_in[4];
    const float* b2 = (const float*)d_in[5];
    const int*   op_rows[4] = { (const int*)d_in[6],  (const int*)d_in[9],
                                (const int*)d_in[12], (const int*)d_in[15] };
    const int*   op_cols[4] = { (const int*)d_in[7],  (const int*)d_in[10],
                                (const int*)d_in[13], (const int*)d_in[16] };
    const float* op_vals[4] = { (const float*)d_in[8],  (const float*)d_in[11],
                                (const float*)d_in[14], (const float*)d_in[17] };
    // d_in[18..20] = Psct (unused: withgres=False)

    // ---- workspace layout (4-byte words) ----
    float* ws = (float*)d_ws;
    size_t off = 0;
    float* B   = ws;                                    off += (size_t)6 * NH;   // 6 fp32 branches [N][128]
    float* att = ws + off;                              off += (size_t)6 * N_NODES;
    unsigned short* Xh = (unsigned short*)(ws + off);   off += NH / 2;           // X fp16 [N][128]
    int*   ptr   = (int*)(ws + off);                    off += N_NODES + 2;
    int*   table = (int*)(ws + off);                    off += TBL + 1;
    int*   part  = (int*)(ws + off);                    off += 1024;
    unsigned short* brnk = (unsigned short*)(ws + off); off += NE / 2;
    if (off & 1) off++;                                 // 8B align
    int2*  tmp   = (int2*)(ws + off);                   off += (size_t)2 * NE;
    int2*  pairs = (int2*)(ws + off);                   off += (size_t)2 * NE;
    // hh (fp16 chain source) aliases tmp: tmp is dead between sort_op(0) and
    // sort_op(1); all chain hops run in that window. mid (fc intermediate)
    // also aliases tmp: dead after the last sort.
    unsigned short* hh = (unsigned short*)tmp;
    float* mid = (float*)tmp;

    float* hp = (float*)d_out;    // hprime output lives in d_out

    dim3 blk(256);
    const int rg = (N_NODES * 32 + 255) / 256;  // 6250
    const int cg = (NH / 4 + 255) / 256;        // 6250
    const int fg = (N_NODES + 63) / 64;         // 782

    auto sort_op = [&](int o) {
        k1_hist<<<NBLK1, blk, 0, stream>>>(op_rows[o], table, brnk);
        s1_partial<<<SB, blk, 0, stream>>>(table, part);
        s2_scan<<<1, 1024, 0, stream>>>(part);
        s3_add<<<SB, blk, 0, stream>>>(table, part);
        k3_scatter<<<NBLK1, blk, 0, stream>>>(op_rows[o], op_cols[o], op_vals[o],
                                              brnk, table, tmp);
        k4_fine<<<NBUK, blk, 0, stream>>>(table, tmp, pairs, ptr);
    };

    cvt_f2h_kernel<<<cg, blk, 0, stream>>>(X, Xh);

    // ---- A chain: all hops gather fp16, store fp32 ----
    sort_op(0);
    spmm_h_kernel<false><<<rg, blk, 0, stream>>>(ptr, pairs, Xh, B + 0 * (size_t)NH);
    cvt_f2h_kernel<<<cg, blk, 0, stream>>>(B + 0 * (size_t)NH, hh);
    spmm_h_kernel<false><<<rg, blk, 0, stream>>>(ptr, pairs, hh, B + 1 * (size_t)NH);
    cvt_f2h_kernel<<<cg, blk, 0, stream>>>(B + 1 * (size_t)NH, hh);
    spmm_h_kernel<false><<<rg, blk, 0, stream>>>(ptr, pairs, hh, B + 2 * (size_t)NH);

    // ---- P1..P3: fp16 gather of X, fp32 store, fused abs ----
    for (int i = 0; i < 3; ++i) {
        sort_op(1 + i);
        spmm_h_kernel<true><<<rg, blk, 0, stream>>>(ptr, pairs, Xh,
                                                    B + (size_t)(3 + i) * NH);
    }

    // ---- attention, hprime, register-tiled FCs ----
    attn_kernel<<<(N_NODES + 3) / 4, blk, 0, stream>>>(X, B, a, att);
    hprime_kernel<<<(NH + 255) / 256, blk, 0, stream>>>(B, att, hp);
    fc_tile_kernel<<<fg, blk, 0, stream>>>(hp,  W1, b1, mid);
    fc_tile_kernel<<<fg, blk, 0, stream>>>(mid, W2, b2, (float*)d_out);
}

// Round 12
// 766.001 us; speedup vs baseline: 1.4944x; 1.1259x over previous
//
#include <hip/hip_runtime.h>
#include <hip/hip_fp16.h>

#define N_NODES 50000
#define HID 128
#define NE 1600000
#define NH (N_NODES * HID)      // 6,400,000 elems per [N,HID] buffer

#define EPB   4096              // edges per K1/K3 block
#define NBLK1 391               // ceil(NE / EPB)
#define NBUK  391               // ceil(N_NODES / 128) row buckets (128 rows each)
#define TBL   (NBUK * NBLK1)    // 152,881 scan table entries
#define SB    ((TBL + 255) / 256)  // 598 scan blocks

typedef _Float16 f16x8 __attribute__((ext_vector_type(8)));
typedef float    f32x4 __attribute__((ext_vector_type(4)));

// ---- fp16 helpers (RNE) ----
__device__ __forceinline__ float h2f(unsigned short u) {
    __half_raw r; r.x = u;
    __half h = r;
    return __half2float(h);
}
__device__ __forceinline__ unsigned short f2h(float f) {
    __half h = __float2half_rn(f);
    __half_raw r = h;
    return r.x;
}

// ===========================================================================
// K1: per-block LDS histogram over 391 coarse buckets + per-edge rank.
// ===========================================================================
__global__ __launch_bounds__(256) void k1_hist(
    const int* __restrict__ rows, int* __restrict__ table,
    unsigned short* __restrict__ rank)
{
    __shared__ int h[NBUK];
    int b = blockIdx.x, t = threadIdx.x;
    for (int i = t; i < NBUK; i += 256) h[i] = 0;
    __syncthreads();
    int e0 = b * EPB;
    int e1 = min(e0 + EPB, NE);
    for (int e = e0 + t; e < e1; e += 256)
        rank[e] = (unsigned short)atomicAdd(&h[rows[e] >> 7], 1);
    __syncthreads();
    for (int i = t; i < NBUK; i += 256) table[i * NBLK1 + b] = h[i];
}

// ===========================================================================
// S1/S2/S3: hierarchical exclusive scan of table[TBL]
// ===========================================================================
__global__ __launch_bounds__(256) void s1_partial(
    const int* __restrict__ table, int* __restrict__ part)
{
    __shared__ int red[256];
    int b = blockIdx.x, t = threadIdx.x;
    int idx = b * 256 + t;
    red[t] = (idx < TBL) ? table[idx] : 0;
    __syncthreads();
    #pragma unroll
    for (int s = 128; s > 0; s >>= 1) {
        if (t < s) red[t] += red[t + s];
        __syncthreads();
    }
    if (t == 0) part[b] = red[0];
}

__global__ __launch_bounds__(1024) void s2_scan(int* __restrict__ part)
{
    __shared__ int sh[1024];
    int t = threadIdx.x;
    sh[t] = (t < SB) ? part[t] : 0;
    __syncthreads();
    for (int off = 1; off < 1024; off <<= 1) {
        int v = (t >= off) ? sh[t - off] : 0;
        __syncthreads();
        sh[t] += v;
        __syncthreads();
    }
    if (t < SB) part[t] = (t == 0) ? 0 : sh[t - 1];
}

__global__ __launch_bounds__(256) void s3_add(
    int* __restrict__ table, const int* __restrict__ part)
{
    __shared__ int sh[256];
    int b = blockIdx.x, t = threadIdx.x;
    int idx = b * 256 + t;
    int v = (idx < TBL) ? table[idx] : 0;
    sh[t] = v;
    __syncthreads();
    #pragma unroll
    for (int off = 1; off < 256; off <<= 1) {
        int u = (t >= off) ? sh[t - off] : 0;
        __syncthreads();
        sh[t] += u;
        __syncthreads();
    }
    int excl = (t == 0) ? 0 : sh[t - 1];
    if (idx < TBL) table[idx] = part[b] + excl;
}

// ===========================================================================
// K3: atomic-free scatter into bucket-partitioned tmp.
// ===========================================================================
__global__ __launch_bounds__(256) void k3_scatter(
    const int* __restrict__ rows, const int* __restrict__ cols,
    const float* __restrict__ vals, const unsigned short* __restrict__ rank,
    const int* __restrict__ table, int2* __restrict__ tmp)
{
    __shared__ int base[NBUK];
    int b = blockIdx.x, t = threadIdx.x;
    for (int i = t; i < NBUK; i += 256) base[i] = table[i * NBLK1 + b];
    __syncthreads();
    int e0 = b * EPB;
    int e1 = min(e0 + EPB, NE);
    for (int e = e0 + t; e < e1; e += 256) {
        int r = rows[e];
        int pos = base[r >> 7] + (int)rank[e];
        tmp[pos] = make_int2(((r & 127) << 16) | cols[e], __float_as_int(vals[e]));
    }
}

// ===========================================================================
// K4: per-bucket fine sort -> final CSR pairs + rowptr.
// ===========================================================================
__global__ __launch_bounds__(256) void k4_fine(
    const int* __restrict__ table, const int2* __restrict__ tmp,
    int2* __restrict__ pairs, int* __restrict__ rowptr)
{
    __shared__ int cnt[128];
    __shared__ int sh[256];
    __shared__ int nxt[128];
    int k = blockIdx.x, t = threadIdx.x;
    if (t < 128) cnt[t] = 0;
    __syncthreads();
    int base = table[k * NBLK1];
    int end  = (k == NBUK - 1) ? NE : table[(k + 1) * NBLK1];
    for (int e = base + t; e < end; e += 256)
        atomicAdd(&cnt[(tmp[e].x >> 16) & 127], 1);
    __syncthreads();
    sh[t] = (t < 128) ? cnt[t] : 0;
    __syncthreads();
    #pragma unroll
    for (int off = 1; off < 256; off <<= 1) {
        int v = (t >= off) ? sh[t - off] : 0;
        __syncthreads();
        sh[t] += v;
        __syncthreads();
    }
    if (t < 128) {
        int excl = (t == 0) ? 0 : sh[t - 1];
        nxt[t] = base + excl;
        int row = k * 128 + t;
        if (row < N_NODES) rowptr[row] = base + excl;
    }
    if (k == NBUK - 1 && t == 255) rowptr[N_NODES] = NE;
    __syncthreads();
    for (int e = base + t; e < end; e += 256) {
        int2 p = tmp[e];
        int pos = atomicAdd(&nxt[(p.x >> 16) & 127], 1);
        pairs[pos] = make_int2(p.x & 0xFFFF, p.y);
    }
}

// ===========================================================================
// cvt: fp32 -> fp16 (RNE), n4 = element count / 4
// ===========================================================================
__global__ __launch_bounds__(256) void cvt_f2h_kernel(
    const float* __restrict__ in, unsigned short* __restrict__ out, int n4)
{
    int i = blockIdx.x * 256 + threadIdx.x;     // float4 id
    if (i >= n4) return;
    float4 v = ((const float4*)in)[i];
    ushort4 o;
    o.x = f2h(v.x); o.y = f2h(v.y); o.z = f2h(v.z); o.w = f2h(v.w);
    ((ushort4*)out)[i] = o;
}

// ===========================================================================
// CSR SpMM with fp16 gather source, fp32 accumulate + fp32 store.
// 32 lanes per row, each lane owns 4 cols (one ushort4 = 8B); 4-way unroll.
// Per edge: 32 lanes x 8B = 256B = 4 cache lines (segment-rate bound).
// ===========================================================================
template <bool ABS>
__global__ __launch_bounds__(256) void spmm_h_kernel(
    const int* __restrict__ rowptr, const int2* __restrict__ pairs,
    const unsigned short* __restrict__ xh, float* __restrict__ y)
{
    int t   = blockIdx.x * 256 + threadIdx.x;
    int r   = t >> 5;
    int sub = t & 31;
    if (r >= N_NODES) return;

    const ushort4* x4 = (const ushort4*)xh + sub;  // row stride = 32 ushort4
    int start = rowptr[r], end = rowptr[r + 1];

    float4 a0 = {0,0,0,0}, a1 = {0,0,0,0};
    float4 a2 = {0,0,0,0}, a3 = {0,0,0,0};

    #define EDGE_H(P, A) { \
        ushort4 _x = x4[(size_t)(P).x * 32]; \
        float _v = __int_as_float((P).y); \
        A.x += _v * h2f(_x.x); \
        A.y += _v * h2f(_x.y); \
        A.z += _v * h2f(_x.z); \
        A.w += _v * h2f(_x.w); }

    int e = start;
    for (; e + 3 < end; e += 4) {
        int2 p0 = pairs[e];
        int2 p1 = pairs[e + 1];
        int2 p2 = pairs[e + 2];
        int2 p3 = pairs[e + 3];
        EDGE_H(p0, a0); EDGE_H(p1, a1); EDGE_H(p2, a2); EDGE_H(p3, a3);
    }
    for (; e < end; ++e) {
        int2 p0 = pairs[e];
        EDGE_H(p0, a0);
    }
    #undef EDGE_H

    float4 acc;
    acc.x = (a0.x + a1.x) + (a2.x + a3.x);
    acc.y = (a0.y + a1.y) + (a2.y + a3.y);
    acc.z = (a0.z + a1.z) + (a2.z + a3.z);
    acc.w = (a0.w + a1.w) + (a2.w + a3.w);
    if (ABS) {
        acc.x = fabsf(acc.x); acc.y = fabsf(acc.y);
        acc.z = fabsf(acc.z); acc.w = fabsf(acc.w);
    }
    ((float4*)(y + (size_t)r * HID))[sub] = acc;
}

// ===========================================================================
// Attention: e[n,b] = dot(relu(pair_b[n]), a); att = softmax over b (6)
// ===========================================================================
__global__ __launch_bounds__(256) void attn_kernel(
    const float* __restrict__ X, const float* __restrict__ B,
    const float* __restrict__ a, float* __restrict__ att)
{
    int wid  = (blockIdx.x * 256 + threadIdx.x) >> 6;
    int lane = threadIdx.x & 63;
    if (wid >= N_NODES) return;

    const float4 av = ((const float4*)a)[lane];
    float e[6];

    if (wid < N_NODES / 2) {
        const float4 p = ((const float4*)(X + (size_t)wid * 256))[lane];
        float s = fmaxf(p.x, 0.f) * av.x + fmaxf(p.y, 0.f) * av.y +
                  fmaxf(p.z, 0.f) * av.z + fmaxf(p.w, 0.f) * av.w;
        #pragma unroll
        for (int m = 1; m < 64; m <<= 1) s += __shfl_xor(s, m);
        #pragma unroll
        for (int b = 0; b < 6; ++b) e[b] = s;
    } else {
        int m = 2 * wid - N_NODES;
        #pragma unroll
        for (int b = 0; b < 6; ++b) {
            const float4 p =
                ((const float4*)(B + (size_t)b * NH + (size_t)m * HID))[lane];
            float s = fmaxf(p.x, 0.f) * av.x + fmaxf(p.y, 0.f) * av.y +
                      fmaxf(p.z, 0.f) * av.z + fmaxf(p.w, 0.f) * av.w;
            #pragma unroll
            for (int k = 1; k < 64; k <<= 1) s += __shfl_xor(s, k);
            e[b] = s;
        }
    }

    if (lane == 0) {
        float mx = e[0];
        #pragma unroll
        for (int b = 1; b < 6; ++b) mx = fmaxf(mx, e[b]);
        float ex[6], sum = 0.f;
        #pragma unroll
        for (int b = 0; b < 6; ++b) { ex[b] = expf(e[b] - mx); sum += ex[b]; }
        float inv = 1.f / sum;
        #pragma unroll
        for (int b = 0; b < 6; ++b) att[(size_t)wid * 6 + b] = ex[b] * inv;
    }
}

// ===========================================================================
// h_prime[n,q] = (1/6) * sum_p att[n,p] * B_{(p*128+q)%6}[n, (p*128+q)/6]
// Output fp16 (feeds the MFMA FC).
// ===========================================================================
__global__ __launch_bounds__(256) void hprime_kernel(
    const float* __restrict__ B, const float* __restrict__ att,
    unsigned short* __restrict__ hp16)
{
    int idx = blockIdx.x * 256 + threadIdx.x;
    if (idx >= NH) return;
    int n = idx >> 7;
    int q = idx & 127;
    float s = 0.f;
    #pragma unroll
    for (int p = 0; p < 6; ++p) {
        int f = p * HID + q;
        int j = f % 6;
        int i = f / 6;
        s += att[(size_t)n * 6 + p] * B[(size_t)j * NH + (size_t)n * HID + i];
    }
    hp16[idx] = f2h(s * (1.0f / 6.0f));
}

// ===========================================================================
// MFMA FC: out[n,o] = leaky_relu(dot(A[n,:], W[o,:]) + b[o]), K=HID=128.
// mfma_f32_16x16x32_f16. Per wave: col-block cb = wid&7 (o = cb*16+lane&15);
// W block held entirely in 16 VGPRs (4 B-frags, hoisted); loop 16-row tiles.
// Fragments (§3): A/B lane&15 = M/N index, k = (lane>>4)*8+j (16B contiguous
// row reads — no LDS). C/D: col = lane&15, row = (lane>>4)*4 + reg [m89].
// ===========================================================================
template <bool OUT16>
__global__ __launch_bounds__(256) void fc_mfma_kernel(
    const unsigned short* __restrict__ Ah,   // [N][128] fp16
    const unsigned short* __restrict__ Wh,   // [128][128] fp16 (row o, k)
    const float* __restrict__ bias,
    void* __restrict__ outp)                 // fp16 [N][128] or fp32 [N][128]
{
    const int wid  = blockIdx.x * 4 + (threadIdx.x >> 6);
    const int lane = threadIdx.x & 63;
    const int cb   = wid & 7;              // col block 0..7
    const int o    = cb * 16 + (lane & 15);
    const int kg   = lane >> 4;            // 0..3
    const int nw   = (gridDim.x * 4) >> 3; // waves per col-block

    f16x8 bfrag[4];
    #pragma unroll
    for (int ks = 0; ks < 4; ++ks)
        bfrag[ks] = *(const f16x8*)(Wh + (size_t)o * HID + ks * 32 + kg * 8);
    const float bo = bias[o];

    for (int tile = wid >> 3; tile < N_NODES / 16; tile += nw) {
        const int n0 = tile * 16;
        const unsigned short* ar =
            Ah + (size_t)(n0 + (lane & 15)) * HID + kg * 8;
        f32x4 acc = {0.f, 0.f, 0.f, 0.f};
        #pragma unroll
        for (int ks = 0; ks < 4; ++ks) {
            f16x8 af = *(const f16x8*)(ar + ks * 32);
            acc = __builtin_amdgcn_mfma_f32_16x16x32_f16(af, bfrag[ks], acc,
                                                         0, 0, 0);
        }
        #pragma unroll
        for (int j = 0; j < 4; ++j) {
            float v = acc[j] + bo;
            v = v > 0.f ? v : 0.01f * v;
            int n = n0 + kg * 4 + j;
            if (OUT16)
                ((unsigned short*)outp)[(size_t)n * HID + o] = f2h(v);
            else
                ((float*)outp)[(size_t)n * HID + o] = v;
        }
    }
}

// ===========================================================================
extern "C" void kernel_launch(void* const* d_in, const int* in_sizes, int n_in,
                              void* d_out, int out_size, void* d_ws, size_t ws_size,
                              hipStream_t stream)
{
    const float* X  = (const float*)d_in[0];
    const float* a  = (const float*)d_in[1];
    const float* W1 = (const float*)d_in[2];
    const float* b1 = (const float*)d_in[3];
    const float* W2 = (const float*)d_in[4];
    const float* b2 = (const float*)d_in[5];
    const int*   op_rows[4] = { (const int*)d_in[6],  (const int*)d_in[9],
                                (const int*)d_in[12], (const int*)d_in[15] };
    const int*   op_cols[4] = { (const int*)d_in[7],  (const int*)d_in[10],
                                (const int*)d_in[13], (const int*)d_in[16] };
    const float* op_vals[4] = { (const float*)d_in[8],  (const float*)d_in[11],
                                (const float*)d_in[14], (const float*)d_in[17] };
    // d_in[18..20] = Psct (unused: withgres=False)

    // ---- workspace layout (4-byte words) ----
    float* ws = (float*)d_ws;
    size_t off = 0;
    float* B   = ws;                                    off += (size_t)6 * NH;   // 6 fp32 branches [N][128]
    float* att = ws + off;                              off += (size_t)6 * N_NODES;
    unsigned short* Xh  = (unsigned short*)(ws + off);  off += NH / 2;           // X fp16
    unsigned short* Wh1 = (unsigned short*)(ws + off);  off += HID * HID / 2;    // W1 fp16
    unsigned short* Wh2 = (unsigned short*)(ws + off);  off += HID * HID / 2;    // W2 fp16
    int*   ptr   = (int*)(ws + off);                    off += N_NODES + 2;
    int*   table = (int*)(ws + off);                    off += TBL + 1;
    int*   part  = (int*)(ws + off);                    off += 1024;
    unsigned short* brnk = (unsigned short*)(ws + off); off += NE / 2;
    off = (off + 3) & ~(size_t)3;                       // 16B align
    int2*  tmp   = (int2*)(ws + off);                   off += (size_t)2 * NE;
    int2*  pairs = (int2*)(ws + off);                   off += (size_t)2 * NE;
    // Aliases (lifetime-disjoint):
    //  hh   (fp16 chain src) = tmp   — used only between sort_op(0) and sort_op(1)
    //  hp16 (hprime out)     = tmp   — tmp dead after last k4_fine
    //  mid16 (fc1 out)       = pairs — pairs dead after last spmm
    unsigned short* hh    = (unsigned short*)tmp;
    unsigned short* hp16  = (unsigned short*)tmp;
    unsigned short* mid16 = (unsigned short*)pairs;

    dim3 blk(256);
    const int rg = (N_NODES * 32 + 255) / 256;  // 6250
    const int cg = (NH / 4 + 255) / 256;        // 6250
    const int wg = (HID * HID / 4 + 255) / 256; // 16

    auto sort_op = [&](int o) {
        k1_hist<<<NBLK1, blk, 0, stream>>>(op_rows[o], table, brnk);
        s1_partial<<<SB, blk, 0, stream>>>(table, part);
        s2_scan<<<1, 1024, 0, stream>>>(part);
        s3_add<<<SB, blk, 0, stream>>>(table, part);
        k3_scatter<<<NBLK1, blk, 0, stream>>>(op_rows[o], op_cols[o], op_vals[o],
                                              brnk, table, tmp);
        k4_fine<<<NBUK, blk, 0, stream>>>(table, tmp, pairs, ptr);
    };

    cvt_f2h_kernel<<<cg, blk, 0, stream>>>(X, Xh, NH / 4);
    cvt_f2h_kernel<<<wg, blk, 0, stream>>>(W1, Wh1, HID * HID / 4);
    cvt_f2h_kernel<<<wg, blk, 0, stream>>>(W2, Wh2, HID * HID / 4);

    // ---- A chain: all hops gather fp16, store fp32 ----
    sort_op(0);
    spmm_h_kernel<false><<<rg, blk, 0, stream>>>(ptr, pairs, Xh, B + 0 * (size_t)NH);
    cvt_f2h_kernel<<<cg, blk, 0, stream>>>(B + 0 * (size_t)NH, hh, NH / 4);
    spmm_h_kernel<false><<<rg, blk, 0, stream>>>(ptr, pairs, hh, B + 1 * (size_t)NH);
    cvt_f2h_kernel<<<cg, blk, 0, stream>>>(B + 1 * (size_t)NH, hh, NH / 4);
    spmm_h_kernel<false><<<rg, blk, 0, stream>>>(ptr, pairs, hh, B + 2 * (size_t)NH);

    // ---- P1..P3: fp16 gather of X, fp32 store, fused abs ----
    for (int i = 0; i < 3; ++i) {
        sort_op(1 + i);
        spmm_h_kernel<true><<<rg, blk, 0, stream>>>(ptr, pairs, Xh,
                                                    B + (size_t)(3 + i) * NH);
    }

    // ---- attention, hprime (fp16 out), MFMA FCs ----
    attn_kernel<<<(N_NODES + 3) / 4, blk, 0, stream>>>(X, B, a, att);
    hprime_kernel<<<(NH + 255) / 256, blk, 0, stream>>>(B, att, hp16);
    fc_mfma_kernel<true ><<<1024, blk, 0, stream>>>(hp16,  Wh1, b1, mid16);
    fc_mfma_kernel<false><<<1024, blk, 0, stream>>>(mid16, Wh2, b2, d_out);
}

// Round 13
// 634.983 us; speedup vs baseline: 1.8027x; 1.2063x over previous
//
#include <hip/hip_runtime.h>
#include <hip/hip_fp16.h>

#define N_NODES 50000
#define HID 128
#define NE 1600000
#define NH (N_NODES * HID)      // 6,400,000 elems per [N,HID] buffer

#define EPB   4096              // edges per K1/K3 block
#define NBLK1 391               // ceil(NE / EPB)
#define NBUK  391               // ceil(N_NODES / 128) row buckets (128 rows each)
#define TBL   (NBUK * NBLK1)    // 152,881 scan table entries
#define SB    ((TBL + 255) / 256)  // 598 scan blocks
#define PTRW  (N_NODES + 2)     // words per rowptr array

typedef _Float16 f16x8 __attribute__((ext_vector_type(8)));
typedef float    f32x4 __attribute__((ext_vector_type(4)));

// ---- fp16 helpers (RNE) ----
__device__ __forceinline__ float h2f(unsigned short u) {
    __half_raw r; r.x = u;
    __half h = r;
    return __half2float(h);
}
__device__ __forceinline__ unsigned short f2h(float f) {
    __half h = __float2half_rn(f);
    __half_raw r = h;
    return r.x;
}

// ===========================================================================
// K1 (batched 4 ops): per-block LDS histogram + per-edge rank.
// ===========================================================================
__global__ __launch_bounds__(256) void k1_hist4(
    const int* __restrict__ r0, const int* __restrict__ r1,
    const int* __restrict__ r2, const int* __restrict__ r3,
    int* __restrict__ table4, unsigned short* __restrict__ rank4)
{
    __shared__ int h[NBUK];
    int o = blockIdx.y, b = blockIdx.x, t = threadIdx.x;
    const int* rows = o == 0 ? r0 : o == 1 ? r1 : o == 2 ? r2 : r3;
    int* table = table4 + (size_t)o * TBL;
    unsigned short* rank = rank4 + (size_t)o * NE;

    for (int i = t; i < NBUK; i += 256) h[i] = 0;
    __syncthreads();
    int e0 = b * EPB;
    int e1 = min(e0 + EPB, NE);
    for (int e = e0 + t; e < e1; e += 256)
        rank[e] = (unsigned short)atomicAdd(&h[rows[e] >> 7], 1);
    __syncthreads();
    for (int i = t; i < NBUK; i += 256) table[i * NBLK1 + b] = h[i];
}

// ===========================================================================
// S1/S2/S3 (batched): hierarchical exclusive scan of each op's table
// ===========================================================================
__global__ __launch_bounds__(256) void s1_partial4(
    const int* __restrict__ table4, int* __restrict__ part4)
{
    __shared__ int red[256];
    int o = blockIdx.y, b = blockIdx.x, t = threadIdx.x;
    const int* table = table4 + (size_t)o * TBL;
    int idx = b * 256 + t;
    red[t] = (idx < TBL) ? table[idx] : 0;
    __syncthreads();
    #pragma unroll
    for (int s = 128; s > 0; s >>= 1) {
        if (t < s) red[t] += red[t + s];
        __syncthreads();
    }
    if (t == 0) part4[o * SB + b] = red[0];
}

__global__ __launch_bounds__(1024) void s2_scan4(int* __restrict__ part4)
{
    __shared__ int sh[1024];
    int o = blockIdx.x, t = threadIdx.x;
    int* part = part4 + o * SB;
    sh[t] = (t < SB) ? part[t] : 0;
    __syncthreads();
    for (int off = 1; off < 1024; off <<= 1) {
        int v = (t >= off) ? sh[t - off] : 0;
        __syncthreads();
        sh[t] += v;
        __syncthreads();
    }
    if (t < SB) part[t] = (t == 0) ? 0 : sh[t - 1];
}

__global__ __launch_bounds__(256) void s3_add4(
    int* __restrict__ table4, const int* __restrict__ part4)
{
    __shared__ int sh[256];
    int o = blockIdx.y, b = blockIdx.x, t = threadIdx.x;
    int* table = table4 + (size_t)o * TBL;
    int idx = b * 256 + t;
    int v = (idx < TBL) ? table[idx] : 0;
    sh[t] = v;
    __syncthreads();
    #pragma unroll
    for (int off = 1; off < 256; off <<= 1) {
        int u = (t >= off) ? sh[t - off] : 0;
        __syncthreads();
        sh[t] += u;
        __syncthreads();
    }
    int excl = (t == 0) ? 0 : sh[t - 1];
    if (idx < TBL) table[idx] = part4[o * SB + b] + excl;
}

// ===========================================================================
// K3: atomic-free scatter into bucket-partitioned tmp (per op).
// ===========================================================================
__global__ __launch_bounds__(256) void k3_scatter(
    const int* __restrict__ rows, const int* __restrict__ cols,
    const float* __restrict__ vals, const unsigned short* __restrict__ rank,
    const int* __restrict__ table, int2* __restrict__ tmp)
{
    __shared__ int base[NBUK];
    int b = blockIdx.x, t = threadIdx.x;
    for (int i = t; i < NBUK; i += 256) base[i] = table[i * NBLK1 + b];
    __syncthreads();
    int e0 = b * EPB;
    int e1 = min(e0 + EPB, NE);
    for (int e = e0 + t; e < e1; e += 256) {
        int r = rows[e];
        int pos = base[r >> 7] + (int)rank[e];
        tmp[pos] = make_int2(((r & 127) << 16) | cols[e], __float_as_int(vals[e]));
    }
}

// ===========================================================================
// K4: per-bucket fine sort -> final CSR pairs + rowptr (per op).
// ===========================================================================
__global__ __launch_bounds__(256) void k4_fine(
    const int* __restrict__ table, const int2* __restrict__ tmp,
    int2* __restrict__ pairs, int* __restrict__ rowptr)
{
    __shared__ int cnt[128];
    __shared__ int sh[256];
    __shared__ int nxt[128];
    int k = blockIdx.x, t = threadIdx.x;
    if (t < 128) cnt[t] = 0;
    __syncthreads();
    int base = table[k * NBLK1];
    int end  = (k == NBUK - 1) ? NE : table[(k + 1) * NBLK1];
    for (int e = base + t; e < end; e += 256)
        atomicAdd(&cnt[(tmp[e].x >> 16) & 127], 1);
    __syncthreads();
    sh[t] = (t < 128) ? cnt[t] : 0;
    __syncthreads();
    #pragma unroll
    for (int off = 1; off < 256; off <<= 1) {
        int v = (t >= off) ? sh[t - off] : 0;
        __syncthreads();
        sh[t] += v;
        __syncthreads();
    }
    if (t < 128) {
        int excl = (t == 0) ? 0 : sh[t - 1];
        nxt[t] = base + excl;
        int row = k * 128 + t;
        if (row < N_NODES) rowptr[row] = base + excl;
    }
    if (k == NBUK - 1 && t == 255) rowptr[N_NODES] = NE;
    __syncthreads();
    for (int e = base + t; e < end; e += 256) {
        int2 p = tmp[e];
        int pos = atomicAdd(&nxt[(p.x >> 16) & 127], 1);
        pairs[pos] = make_int2(p.x & 0xFFFF, p.y);
    }
}

// ===========================================================================
// cvt: fp32 -> fp16 (RNE), n4 = element count / 4
// ===========================================================================
__global__ __launch_bounds__(256) void cvt_f2h_kernel(
    const float* __restrict__ in, unsigned short* __restrict__ out, int n4)
{
    int i = blockIdx.x * 256 + threadIdx.x;
    if (i >= n4) return;
    float4 v = ((const float4*)in)[i];
    ushort4 o;
    o.x = f2h(v.x); o.y = f2h(v.y); o.z = f2h(v.z); o.w = f2h(v.w);
    ((ushort4*)out)[i] = o;
}

// ===========================================================================
// SpMM row core: fp16 gather, fp32 accumulate, fp16 store.
// 32 lanes per row; lane owns 4 cols (8B); 4-way unrolled edge loop.
// ===========================================================================
__device__ __forceinline__ void spmm_row(
    const unsigned short* __restrict__ xh, const int2* __restrict__ pairs,
    int start, int end, int sub, bool do_abs,
    unsigned short* __restrict__ yrow)
{
    const ushort4* x4 = (const ushort4*)xh + sub;  // row stride = 32 ushort4

    float4 a0 = {0,0,0,0}, a1 = {0,0,0,0};
    float4 a2 = {0,0,0,0}, a3 = {0,0,0,0};

    #define EDGE_H(P, A) { \
        ushort4 _x = x4[(size_t)(P).x * 32]; \
        float _v = __int_as_float((P).y); \
        A.x += _v * h2f(_x.x); \
        A.y += _v * h2f(_x.y); \
        A.z += _v * h2f(_x.z); \
        A.w += _v * h2f(_x.w); }

    int e = start;
    for (; e + 3 < end; e += 4) {
        int2 p0 = pairs[e];
        int2 p1 = pairs[e + 1];
        int2 p2 = pairs[e + 2];
        int2 p3 = pairs[e + 3];
        EDGE_H(p0, a0); EDGE_H(p1, a1); EDGE_H(p2, a2); EDGE_H(p3, a3);
    }
    for (; e < end; ++e) {
        int2 p0 = pairs[e];
        EDGE_H(p0, a0);
    }
    #undef EDGE_H

    float4 acc;
    acc.x = (a0.x + a1.x) + (a2.x + a3.x);
    acc.y = (a0.y + a1.y) + (a2.y + a3.y);
    acc.z = (a0.z + a1.z) + (a2.z + a3.z);
    acc.w = (a0.w + a1.w) + (a2.w + a3.w);
    if (do_abs) {
        acc.x = fabsf(acc.x); acc.y = fabsf(acc.y);
        acc.z = fabsf(acc.z); acc.w = fabsf(acc.w);
    }
    ushort4 o;
    o.x = f2h(acc.x); o.y = f2h(acc.y); o.z = f2h(acc.z); o.w = f2h(acc.w);
    ((ushort4*)yrow)[sub] = o;
}

// ===========================================================================
// Fused first-hop SpMM: 4 operators (A, P1, P2, P3), all gathering Xh.
// bid & 3 = op (adjacent blocks = different ops -> L2 temporal reuse of Xh).
// dst branch: op 0 -> 0 (h_A); op 1..3 -> 3..5 (|P_i X|).
// ===========================================================================
__global__ __launch_bounds__(256) void spmm4_kernel(
    const int* __restrict__ ptr4, const int2* __restrict__ pairs4,
    const unsigned short* __restrict__ Xh, unsigned short* __restrict__ B16)
{
    int bid = blockIdx.x;
    int op  = bid & 3;
    int rb  = bid >> 2;
    int r   = rb * 8 + (threadIdx.x >> 5);
    int sub = threadIdx.x & 31;
    if (r >= N_NODES) return;

    const int*  ptr   = ptr4 + (size_t)op * PTRW;
    const int2* pairs = pairs4 + (size_t)op * NE;
    int dst = op ? op + 2 : 0;
    unsigned short* yrow = B16 + (size_t)dst * NH + (size_t)r * HID;

    spmm_row(Xh, pairs, ptr[r], ptr[r + 1], sub, op != 0, yrow);
}

// ===========================================================================
// Chain-hop SpMM (single op, no abs): src16 -> dst16 using A's CSR.
// ===========================================================================
__global__ __launch_bounds__(256) void spmm_chain_kernel(
    const int* __restrict__ ptr, const int2* __restrict__ pairs,
    const unsigned short* __restrict__ src16, unsigned short* __restrict__ dst16)
{
    int t   = blockIdx.x * 256 + threadIdx.x;
    int r   = t >> 5;
    int sub = t & 31;
    if (r >= N_NODES) return;
    spmm_row(src16, pairs, ptr[r], ptr[r + 1], sub, false,
             dst16 + (size_t)r * HID);
}

// ===========================================================================
// Attention: e[n,b] = dot(relu(pair_b[n]), a); att = softmax over b (6).
// Branches fp16 [6][N][128]; X fp32.
// ===========================================================================
__global__ __launch_bounds__(256) void attn_kernel(
    const float* __restrict__ X, const unsigned short* __restrict__ B16,
    const float* __restrict__ a, float* __restrict__ att)
{
    int wid  = (blockIdx.x * 256 + threadIdx.x) >> 6;
    int lane = threadIdx.x & 63;
    if (wid >= N_NODES) return;

    const float4 av = ((const float4*)a)[lane];
    float e[6];

    if (wid < N_NODES / 2) {
        const float4 p = ((const float4*)(X + (size_t)wid * 256))[lane];
        float s = fmaxf(p.x, 0.f) * av.x + fmaxf(p.y, 0.f) * av.y +
                  fmaxf(p.z, 0.f) * av.z + fmaxf(p.w, 0.f) * av.w;
        #pragma unroll
        for (int m = 1; m < 64; m <<= 1) s += __shfl_xor(s, m);
        #pragma unroll
        for (int b = 0; b < 6; ++b) e[b] = s;
    } else {
        int m = 2 * wid - N_NODES;
        #pragma unroll
        for (int b = 0; b < 6; ++b) {
            ushort4 u = ((const ushort4*)(B16 + (size_t)b * NH +
                                          (size_t)m * HID))[lane];
            float s = fmaxf(h2f(u.x), 0.f) * av.x + fmaxf(h2f(u.y), 0.f) * av.y +
                      fmaxf(h2f(u.z), 0.f) * av.z + fmaxf(h2f(u.w), 0.f) * av.w;
            #pragma unroll
            for (int k = 1; k < 64; k <<= 1) s += __shfl_xor(s, k);
            e[b] = s;
        }
    }

    if (lane == 0) {
        float mx = e[0];
        #pragma unroll
        for (int b = 1; b < 6; ++b) mx = fmaxf(mx, e[b]);
        float ex[6], sum = 0.f;
        #pragma unroll
        for (int b = 0; b < 6; ++b) { ex[b] = expf(e[b] - mx); sum += ex[b]; }
        float inv = 1.f / sum;
        #pragma unroll
        for (int b = 0; b < 6; ++b) att[(size_t)wid * 6 + b] = ex[b] * inv;
    }
}

// ===========================================================================
// h_prime[n,q] = (1/6) * sum_p att[n,p] * B_{(p*128+q)%6}[n, (p*128+q)/6]
// Branches fp16; output fp16 (feeds MFMA FC).
// ===========================================================================
__global__ __launch_bounds__(256) void hprime_kernel(
    const unsigned short* __restrict__ B16, const float* __restrict__ att,
    unsigned short* __restrict__ hp16)
{
    int idx = blockIdx.x * 256 + threadIdx.x;
    if (idx >= NH) return;
    int n = idx >> 7;
    int q = idx & 127;
    float s = 0.f;
    #pragma unroll
    for (int p = 0; p < 6; ++p) {
        int f = p * HID + q;
        int j = f % 6;
        int i = f / 6;
        s += att[(size_t)n * 6 + p] *
             h2f(B16[(size_t)j * NH + (size_t)n * HID + i]);
    }
    hp16[idx] = f2h(s * (1.0f / 6.0f));
}

// ===========================================================================
// MFMA FC: out[n,o] = leaky_relu(dot(A[n,:], W[o,:]) + b[o]), K=HID=128.
// mfma_f32_16x16x32_f16; W col-block in 16 VGPRs (hoisted); no LDS.
// ===========================================================================
template <bool OUT16>
__global__ __launch_bounds__(256) void fc_mfma_kernel(
    const unsigned short* __restrict__ Ah,
    const unsigned short* __restrict__ Wh,
    const float* __restrict__ bias,
    void* __restrict__ outp)
{
    const int wid  = blockIdx.x * 4 + (threadIdx.x >> 6);
    const int lane = threadIdx.x & 63;
    const int cb   = wid & 7;
    const int o    = cb * 16 + (lane & 15);
    const int kg   = lane >> 4;
    const int nw   = (gridDim.x * 4) >> 3;

    f16x8 bfrag[4];
    #pragma unroll
    for (int ks = 0; ks < 4; ++ks)
        bfrag[ks] = *(const f16x8*)(Wh + (size_t)o * HID + ks * 32 + kg * 8);
    const float bo = bias[o];

    for (int tile = wid >> 3; tile < N_NODES / 16; tile += nw) {
        const int n0 = tile * 16;
        const unsigned short* ar =
            Ah + (size_t)(n0 + (lane & 15)) * HID + kg * 8;
        f32x4 acc = {0.f, 0.f, 0.f, 0.f};
        #pragma unroll
        for (int ks = 0; ks < 4; ++ks) {
            f16x8 af = *(const f16x8*)(ar + ks * 32);
            acc = __builtin_amdgcn_mfma_f32_16x16x32_f16(af, bfrag[ks], acc,
                                                         0, 0, 0);
        }
        #pragma unroll
        for (int j = 0; j < 4; ++j) {
            float v = acc[j] + bo;
            v = v > 0.f ? v : 0.01f * v;
            int n = n0 + kg * 4 + j;
            if (OUT16)
                ((unsigned short*)outp)[(size_t)n * HID + o] = f2h(v);
            else
                ((float*)outp)[(size_t)n * HID + o] = v;
        }
    }
}

// ===========================================================================
extern "C" void kernel_launch(void* const* d_in, const int* in_sizes, int n_in,
                              void* d_out, int out_size, void* d_ws, size_t ws_size,
                              hipStream_t stream)
{
    const float* X  = (const float*)d_in[0];
    const float* a  = (const float*)d_in[1];
    const float* W1 = (const float*)d_in[2];
    const float* b1 = (const float*)d_in[3];
    const float* W2 = (const float*)d_in[4];
    const float* b2 = (const float*)d_in[5];
    const int*   op_rows[4] = { (const int*)d_in[6],  (const int*)d_in[9],
                                (const int*)d_in[12], (const int*)d_in[15] };
    const int*   op_cols[4] = { (const int*)d_in[7],  (const int*)d_in[10],
                                (const int*)d_in[13], (const int*)d_in[16] };
    const float* op_vals[4] = { (const float*)d_in[8],  (const float*)d_in[11],
                                (const float*)d_in[14], (const float*)d_in[17] };
    // d_in[18..20] = Psct (unused: withgres=False)

    // ---- workspace layout (4-byte words); ~171 MB total ----
    float* ws = (float*)d_ws;
    size_t off = 0;
    unsigned short* B16 = (unsigned short*)(ws + off);  off += (size_t)6 * NH / 2; // 6 fp16 branches
    float* att = ws + off;                              off += (size_t)6 * N_NODES;
    unsigned short* Xh  = (unsigned short*)(ws + off);  off += NH / 2;
    unsigned short* Wh1 = (unsigned short*)(ws + off);  off += HID * HID / 2;
    unsigned short* Wh2 = (unsigned short*)(ws + off);  off += HID * HID / 2;
    int*   ptr4   = (int*)(ws + off);                   off += (size_t)4 * PTRW;
    int*   table4 = (int*)(ws + off);                   off += (size_t)4 * TBL;
    int*   part4  = (int*)(ws + off);                   off += 4 * SB + 8;
    unsigned short* rank4 = (unsigned short*)(ws + off); off += (size_t)4 * NE / 2;
    off = (off + 3) & ~(size_t)3;                       // 16B align
    int2*  tmp    = (int2*)(ws + off);                  off += (size_t)2 * NE;
    int2*  pairs4 = (int2*)(ws + off);                  off += (size_t)8 * NE;
    // Aliases (lifetime-disjoint):
    //  hp16 (hprime out) = tmp    — tmp dead after last k4_fine
    //  mid16 (fc1 out)   = pairs4 — pairs dead after last chain spmm
    unsigned short* hp16  = (unsigned short*)tmp;
    unsigned short* mid16 = (unsigned short*)pairs4;

    dim3 blk(256);
    const int rg = (N_NODES * 32 + 255) / 256;  // 6250
    const int cg = (NH / 4 + 255) / 256;        // 6250
    const int wg = (HID * HID / 4 + 255) / 256; // 16

    // ---- conversions ----
    cvt_f2h_kernel<<<cg, blk, 0, stream>>>(X, Xh, NH / 4);
    cvt_f2h_kernel<<<wg, blk, 0, stream>>>(W1, Wh1, HID * HID / 4);
    cvt_f2h_kernel<<<wg, blk, 0, stream>>>(W2, Wh2, HID * HID / 4);

    // ---- batched sort front: 4 histograms + 4 scans in 4 dispatches ----
    k1_hist4<<<dim3(NBLK1, 4), blk, 0, stream>>>(
        op_rows[0], op_rows[1], op_rows[2], op_rows[3], table4, rank4);
    s1_partial4<<<dim3(SB, 4), blk, 0, stream>>>(table4, part4);
    s2_scan4<<<4, 1024, 0, stream>>>(part4);
    s3_add4<<<dim3(SB, 4), blk, 0, stream>>>(table4, part4);

    // ---- per-op scatter + fine sort (shared tmp, per-op pairs/ptr) ----
    for (int o = 0; o < 4; ++o) {
        k3_scatter<<<NBLK1, blk, 0, stream>>>(
            op_rows[o], op_cols[o], op_vals[o],
            rank4 + (size_t)o * NE, table4 + (size_t)o * TBL, tmp);
        k4_fine<<<NBUK, blk, 0, stream>>>(
            table4 + (size_t)o * TBL, tmp,
            pairs4 + (size_t)o * NE, ptr4 + (size_t)o * PTRW);
    }

    // ---- fused first-hop spmm (A,P1,P2,P3 all gather Xh; L2 reuse) ----
    spmm4_kernel<<<rg * 4, blk, 0, stream>>>(ptr4, pairs4, Xh, B16);

    // ---- chain hops 2,3 (A's CSR; fp16 in/out) ----
    spmm_chain_kernel<<<rg, blk, 0, stream>>>(ptr4, pairs4,
                                              B16 + 0 * (size_t)NH,
                                              B16 + 1 * (size_t)NH);
    spmm_chain_kernel<<<rg, blk, 0, stream>>>(ptr4, pairs4,
                                              B16 + 1 * (size_t)NH,
                                              B16 + 2 * (size_t)NH);

    // ---- attention, hprime, MFMA FCs ----
    attn_kernel<<<(N_NODES + 3) / 4, blk, 0, stream>>>(X, B16, a, att);
    hprime_kernel<<<(NH + 255) / 256, blk, 0, stream>>>(B16, att, hp16);
    fc_mfma_kernel<true ><<<1024, blk, 0, stream>>>(hp16,  Wh1, b1, mid16);
    fc_mfma_kernel<false><<<1024, blk, 0, stream>>>(mid16, Wh2, b2, d_out);
}

// Round 14
// 611.491 us; speedup vs baseline: 1.8719x; 1.0384x over previous
//
#include <hip/hip_runtime.h>
#include <hip/hip_fp16.h>

#define N_NODES 50000
#define HID 128
#define NE 1600000
#define NH (N_NODES * HID)      // 6,400,000 elems per [N,HID] buffer

#define EPB   8192              // edges per K1/K3 block
#define NBLK1 196               // ceil(NE / EPB)
#define NBUK  391               // ceil(N_NODES / 128) row buckets (128 rows each)
#define TBL   (NBUK * NBLK1)    // 76,636 scan table entries per op
#define SB    ((TBL + 255) / 256)  // 300 scan blocks per op
#define PTRW  (N_NODES + 2)     // words per rowptr array

typedef _Float16 f16x8 __attribute__((ext_vector_type(8)));
typedef float    f32x4 __attribute__((ext_vector_type(4)));

// ---- fp16 helpers (RNE) ----
__device__ __forceinline__ float h2f(unsigned short u) {
    __half_raw r; r.x = u;
    __half h = r;
    return __half2float(h);
}
__device__ __forceinline__ unsigned short f2h(float f) {
    __half h = __float2half_rn(f);
    __half_raw r = h;
    return r.x;
}

// ===========================================================================
// K1 (batched 4 ops): per-block LDS histogram + per-edge rank.
// ===========================================================================
__global__ __launch_bounds__(256) void k1_hist4(
    const int* __restrict__ r0, const int* __restrict__ r1,
    const int* __restrict__ r2, const int* __restrict__ r3,
    int* __restrict__ table4, unsigned short* __restrict__ rank4)
{
    __shared__ int h[NBUK];
    int o = blockIdx.y, b = blockIdx.x, t = threadIdx.x;
    const int* rows = o == 0 ? r0 : o == 1 ? r1 : o == 2 ? r2 : r3;
    int* table = table4 + (size_t)o * TBL;
    unsigned short* rank = rank4 + (size_t)o * NE;

    for (int i = t; i < NBUK; i += 256) h[i] = 0;
    __syncthreads();
    int e0 = b * EPB;
    int e1 = min(e0 + EPB, NE);
    for (int e = e0 + t; e < e1; e += 256)
        rank[e] = (unsigned short)atomicAdd(&h[rows[e] >> 7], 1);
    __syncthreads();
    for (int i = t; i < NBUK; i += 256) table[i * NBLK1 + b] = h[i];
}

// ===========================================================================
// S1/S2/S3 (batched): hierarchical exclusive scan of each op's table
// ===========================================================================
__global__ __launch_bounds__(256) void s1_partial4(
    const int* __restrict__ table4, int* __restrict__ part4)
{
    __shared__ int red[256];
    int o = blockIdx.y, b = blockIdx.x, t = threadIdx.x;
    const int* table = table4 + (size_t)o * TBL;
    int idx = b * 256 + t;
    red[t] = (idx < TBL) ? table[idx] : 0;
    __syncthreads();
    #pragma unroll
    for (int s = 128; s > 0; s >>= 1) {
        if (t < s) red[t] += red[t + s];
        __syncthreads();
    }
    if (t == 0) part4[o * SB + b] = red[0];
}

__global__ __launch_bounds__(1024) void s2_scan4(int* __restrict__ part4)
{
    __shared__ int sh[1024];
    int o = blockIdx.x, t = threadIdx.x;
    int* part = part4 + o * SB;
    sh[t] = (t < SB) ? part[t] : 0;
    __syncthreads();
    for (int off = 1; off < 1024; off <<= 1) {
        int v = (t >= off) ? sh[t - off] : 0;
        __syncthreads();
        sh[t] += v;
        __syncthreads();
    }
    if (t < SB) part[t] = (t == 0) ? 0 : sh[t - 1];
}

__global__ __launch_bounds__(256) void s3_add4(
    int* __restrict__ table4, const int* __restrict__ part4)
{
    __shared__ int sh[256];
    int o = blockIdx.y, b = blockIdx.x, t = threadIdx.x;
    int* table = table4 + (size_t)o * TBL;
    int idx = b * 256 + t;
    int v = (idx < TBL) ? table[idx] : 0;
    sh[t] = v;
    __syncthreads();
    #pragma unroll
    for (int off = 1; off < 256; off <<= 1) {
        int u = (t >= off) ? sh[t - off] : 0;
        __syncthreads();
        sh[t] += u;
        __syncthreads();
    }
    int excl = (t == 0) ? 0 : sh[t - 1];
    if (idx < TBL) table[idx] = part4[o * SB + b] + excl;
}

// ===========================================================================
// K3 (batched): atomic-free scatter into bucket-partitioned tmp.
// tmp entry: .x = row&127, .y = col<<16 | fp16(val)
// ===========================================================================
__global__ __launch_bounds__(256) void k3_scatter4(
    const int* __restrict__ r0, const int* __restrict__ r1,
    const int* __restrict__ r2, const int* __restrict__ r3,
    const int* __restrict__ c0, const int* __restrict__ c1,
    const int* __restrict__ c2, const int* __restrict__ c3,
    const float* __restrict__ v0, const float* __restrict__ v1,
    const float* __restrict__ v2, const float* __restrict__ v3,
    const unsigned short* __restrict__ rank4,
    const int* __restrict__ table4, int2* __restrict__ tmp4)
{
    __shared__ int base[NBUK];
    int o = blockIdx.y, b = blockIdx.x, t = threadIdx.x;
    const int*   rows = o == 0 ? r0 : o == 1 ? r1 : o == 2 ? r2 : r3;
    const int*   cols = o == 0 ? c0 : o == 1 ? c1 : o == 2 ? c2 : c3;
    const float* vals = o == 0 ? v0 : o == 1 ? v1 : o == 2 ? v2 : v3;
    const int* table = table4 + (size_t)o * TBL;
    const unsigned short* rank = rank4 + (size_t)o * NE;
    int2* tmp = tmp4 + (size_t)o * NE;

    for (int i = t; i < NBUK; i += 256) base[i] = table[i * NBLK1 + b];
    __syncthreads();
    int e0 = b * EPB;
    int e1 = min(e0 + EPB, NE);
    for (int e = e0 + t; e < e1; e += 256) {
        int r = rows[e];
        int pos = base[r >> 7] + (int)rank[e];
        unsigned pk = ((unsigned)cols[e] << 16) | (unsigned)f2h(vals[e]);
        tmp[pos] = make_int2(r & 127, (int)pk);
    }
}

// ===========================================================================
// K4 (batched): per-bucket fine sort -> packed pairs (4B) + rowptr.
// ===========================================================================
__global__ __launch_bounds__(256) void k4_fine4(
    const int* __restrict__ table4, const int2* __restrict__ tmp4,
    unsigned* __restrict__ pairs4, int* __restrict__ ptr4)
{
    __shared__ int cnt[128];
    __shared__ int sh[256];
    __shared__ int nxt[128];
    int o = blockIdx.y, k = blockIdx.x, t = threadIdx.x;
    const int* table = table4 + (size_t)o * TBL;
    const int2* tmp = tmp4 + (size_t)o * NE;
    unsigned* pairs = pairs4 + (size_t)o * NE;
    int* rowptr = ptr4 + (size_t)o * PTRW;

    if (t < 128) cnt[t] = 0;
    __syncthreads();
    int base = table[k * NBLK1];
    int end  = (k == NBUK - 1) ? NE : table[(k + 1) * NBLK1];
    for (int e = base + t; e < end; e += 256)
        atomicAdd(&cnt[tmp[e].x], 1);
    __syncthreads();
    sh[t] = (t < 128) ? cnt[t] : 0;
    __syncthreads();
    #pragma unroll
    for (int off = 1; off < 256; off <<= 1) {
        int v = (t >= off) ? sh[t - off] : 0;
        __syncthreads();
        sh[t] += v;
        __syncthreads();
    }
    if (t < 128) {
        int excl = (t == 0) ? 0 : sh[t - 1];
        nxt[t] = base + excl;
        int row = k * 128 + t;
        if (row < N_NODES) rowptr[row] = base + excl;
    }
    if (k == NBUK - 1 && t == 255) rowptr[N_NODES] = NE;
    __syncthreads();
    for (int e = base + t; e < end; e += 256) {
        int2 p = tmp[e];
        int pos = atomicAdd(&nxt[p.x], 1);
        pairs[pos] = (unsigned)p.y;
    }
}

// ===========================================================================
// cvt: fp32 -> fp16 (RNE), n4 = element count / 4
// ===========================================================================
__global__ __launch_bounds__(256) void cvt_f2h_kernel(
    const float* __restrict__ in, unsigned short* __restrict__ out, int n4)
{
    int i = blockIdx.x * 256 + threadIdx.x;
    if (i >= n4) return;
    float4 v = ((const float4*)in)[i];
    ushort4 o;
    o.x = f2h(v.x); o.y = f2h(v.y); o.z = f2h(v.z); o.w = f2h(v.w);
    ((ushort4*)out)[i] = o;
}

// ===========================================================================
// SpMM row core: packed 4B edges (col<<16|fp16 val), fp16 gather,
// fp32 accumulate, fp16 store. 32 lanes per row; 4-way unrolled.
// ===========================================================================
__device__ __forceinline__ void spmm_row(
    const unsigned short* __restrict__ xh, const unsigned* __restrict__ pairs,
    int start, int end, int sub, bool do_abs,
    unsigned short* __restrict__ yrow)
{
    const ushort4* x4 = (const ushort4*)xh + sub;  // row stride = 32 ushort4

    float4 a0 = {0,0,0,0}, a1 = {0,0,0,0};
    float4 a2 = {0,0,0,0}, a3 = {0,0,0,0};

    #define EDGE_P(P, A) { \
        unsigned _p = (P); \
        float _v = h2f((unsigned short)(_p & 0xFFFFu)); \
        ushort4 _x = x4[(size_t)(_p >> 16) * 32]; \
        A.x += _v * h2f(_x.x); \
        A.y += _v * h2f(_x.y); \
        A.z += _v * h2f(_x.z); \
        A.w += _v * h2f(_x.w); }

    int e = start;
    for (; e + 3 < end; e += 4) {
        unsigned p0 = pairs[e];
        unsigned p1 = pairs[e + 1];
        unsigned p2 = pairs[e + 2];
        unsigned p3 = pairs[e + 3];
        EDGE_P(p0, a0); EDGE_P(p1, a1); EDGE_P(p2, a2); EDGE_P(p3, a3);
    }
    for (; e < end; ++e) {
        EDGE_P(pairs[e], a0);
    }
    #undef EDGE_P

    float4 acc;
    acc.x = (a0.x + a1.x) + (a2.x + a3.x);
    acc.y = (a0.y + a1.y) + (a2.y + a3.y);
    acc.z = (a0.z + a1.z) + (a2.z + a3.z);
    acc.w = (a0.w + a1.w) + (a2.w + a3.w);
    if (do_abs) {
        acc.x = fabsf(acc.x); acc.y = fabsf(acc.y);
        acc.z = fabsf(acc.z); acc.w = fabsf(acc.w);
    }
    ushort4 o;
    o.x = f2h(acc.x); o.y = f2h(acc.y); o.z = f2h(acc.z); o.w = f2h(acc.w);
    ((ushort4*)yrow)[sub] = o;
}

// ===========================================================================
// Fused first-hop SpMM: 4 operators (A, P1, P2, P3), all gathering Xh.
// bid & 3 = op (adjacent blocks = different ops -> L2 temporal reuse of Xh).
// ===========================================================================
__global__ __launch_bounds__(256) void spmm4_kernel(
    const int* __restrict__ ptr4, const unsigned* __restrict__ pairs4,
    const unsigned short* __restrict__ Xh, unsigned short* __restrict__ B16)
{
    int bid = blockIdx.x;
    int op  = bid & 3;
    int rb  = bid >> 2;
    int r   = rb * 8 + (threadIdx.x >> 5);
    int sub = threadIdx.x & 31;
    if (r >= N_NODES) return;

    const int*      ptr   = ptr4 + (size_t)op * PTRW;
    const unsigned* pairs = pairs4 + (size_t)op * NE;
    int dst = op ? op + 2 : 0;
    unsigned short* yrow = B16 + (size_t)dst * NH + (size_t)r * HID;

    spmm_row(Xh, pairs, ptr[r], ptr[r + 1], sub, op != 0, yrow);
}

// ===========================================================================
// Chain-hop SpMM (A's CSR, no abs): src16 -> dst16.
// ===========================================================================
__global__ __launch_bounds__(256) void spmm_chain_kernel(
    const int* __restrict__ ptr, const unsigned* __restrict__ pairs,
    const unsigned short* __restrict__ src16, unsigned short* __restrict__ dst16)
{
    int t   = blockIdx.x * 256 + threadIdx.x;
    int r   = t >> 5;
    int sub = t & 31;
    if (r >= N_NODES) return;
    spmm_row(src16, pairs, ptr[r], ptr[r + 1], sub, false,
             dst16 + (size_t)r * HID);
}

// ===========================================================================
// Attention: e[n,b] = dot(relu(pair_b[n]), a); att = softmax over b (6).
// ===========================================================================
__global__ __launch_bounds__(256) void attn_kernel(
    const float* __restrict__ X, const unsigned short* __restrict__ B16,
    const float* __restrict__ a, float* __restrict__ att)
{
    int wid  = (blockIdx.x * 256 + threadIdx.x) >> 6;
    int lane = threadIdx.x & 63;
    if (wid >= N_NODES) return;

    const float4 av = ((const float4*)a)[lane];
    float e[6];

    if (wid < N_NODES / 2) {
        const float4 p = ((const float4*)(X + (size_t)wid * 256))[lane];
        float s = fmaxf(p.x, 0.f) * av.x + fmaxf(p.y, 0.f) * av.y +
                  fmaxf(p.z, 0.f) * av.z + fmaxf(p.w, 0.f) * av.w;
        #pragma unroll
        for (int m = 1; m < 64; m <<= 1) s += __shfl_xor(s, m);
        #pragma unroll
        for (int b = 0; b < 6; ++b) e[b] = s;
    } else {
        int m = 2 * wid - N_NODES;
        #pragma unroll
        for (int b = 0; b < 6; ++b) {
            ushort4 u = ((const ushort4*)(B16 + (size_t)b * NH +
                                          (size_t)m * HID))[lane];
            float s = fmaxf(h2f(u.x), 0.f) * av.x + fmaxf(h2f(u.y), 0.f) * av.y +
                      fmaxf(h2f(u.z), 0.f) * av.z + fmaxf(h2f(u.w), 0.f) * av.w;
            #pragma unroll
            for (int k = 1; k < 64; k <<= 1) s += __shfl_xor(s, k);
            e[b] = s;
        }
    }

    if (lane == 0) {
        float mx = e[0];
        #pragma unroll
        for (int b = 1; b < 6; ++b) mx = fmaxf(mx, e[b]);
        float ex[6], sum = 0.f;
        #pragma unroll
        for (int b = 0; b < 6; ++b) { ex[b] = expf(e[b] - mx); sum += ex[b]; }
        float inv = 1.f / sum;
        #pragma unroll
        for (int b = 0; b < 6; ++b) att[(size_t)wid * 6 + b] = ex[b] * inv;
    }
}

// ===========================================================================
// h_prime[n,q] = (1/6) * sum_p att[n,p] * B_{(p*128+q)%6}[n, (p*128+q)/6]
// ===========================================================================
__global__ __launch_bounds__(256) void hprime_kernel(
    const unsigned short* __restrict__ B16, const float* __restrict__ att,
    unsigned short* __restrict__ hp16)
{
    int idx = blockIdx.x * 256 + threadIdx.x;
    if (idx >= NH) return;
    int n = idx >> 7;
    int q = idx & 127;
    float s = 0.f;
    #pragma unroll
    for (int p = 0; p < 6; ++p) {
        int f = p * HID + q;
        int j = f % 6;
        int i = f / 6;
        s += att[(size_t)n * 6 + p] *
             h2f(B16[(size_t)j * NH + (size_t)n * HID + i]);
    }
    hp16[idx] = f2h(s * (1.0f / 6.0f));
}

// ===========================================================================
// MFMA FC: out[n,o] = leaky_relu(dot(A[n,:], W[o,:]) + b[o]), K=HID=128.
// ===========================================================================
template <bool OUT16>
__global__ __launch_bounds__(256) void fc_mfma_kernel(
    const unsigned short* __restrict__ Ah,
    const unsigned short* __restrict__ Wh,
    const float* __restrict__ bias,
    void* __restrict__ outp)
{
    const int wid  = blockIdx.x * 4 + (threadIdx.x >> 6);
    const int lane = threadIdx.x & 63;
    const int cb   = wid & 7;
    const int o    = cb * 16 + (lane & 15);
    const int kg   = lane >> 4;
    const int nw   = (gridDim.x * 4) >> 3;

    f16x8 bfrag[4];
    #pragma unroll
    for (int ks = 0; ks < 4; ++ks)
        bfrag[ks] = *(const f16x8*)(Wh + (size_t)o * HID + ks * 32 + kg * 8);
    const float bo = bias[o];

    for (int tile = wid >> 3; tile < N_NODES / 16; tile += nw) {
        const int n0 = tile * 16;
        const unsigned short* ar =
            Ah + (size_t)(n0 + (lane & 15)) * HID + kg * 8;
        f32x4 acc = {0.f, 0.f, 0.f, 0.f};
        #pragma unroll
        for (int ks = 0; ks < 4; ++ks) {
            f16x8 af = *(const f16x8*)(ar + ks * 32);
            acc = __builtin_amdgcn_mfma_f32_16x16x32_f16(af, bfrag[ks], acc,
                                                         0, 0, 0);
        }
        #pragma unroll
        for (int j = 0; j < 4; ++j) {
            float v = acc[j] + bo;
            v = v > 0.f ? v : 0.01f * v;
            int n = n0 + kg * 4 + j;
            if (OUT16)
                ((unsigned short*)outp)[(size_t)n * HID + o] = f2h(v);
            else
                ((float*)outp)[(size_t)n * HID + o] = v;
        }
    }
}

// ===========================================================================
extern "C" void kernel_launch(void* const* d_in, const int* in_sizes, int n_in,
                              void* d_out, int out_size, void* d_ws, size_t ws_size,
                              hipStream_t stream)
{
    const float* X  = (const float*)d_in[0];
    const float* a  = (const float*)d_in[1];
    const float* W1 = (const float*)d_in[2];
    const float* b1 = (const float*)d_in[3];
    const float* W2 = (const float*)d_in[4];
    const float* b2 = (const float*)d_in[5];
    const int*   op_rows[4] = { (const int*)d_in[6],  (const int*)d_in[9],
                                (const int*)d_in[12], (const int*)d_in[15] };
    const int*   op_cols[4] = { (const int*)d_in[7],  (const int*)d_in[10],
                                (const int*)d_in[13], (const int*)d_in[16] };
    const float* op_vals[4] = { (const float*)d_in[8],  (const float*)d_in[11],
                                (const float*)d_in[14], (const float*)d_in[17] };
    // d_in[18..20] = Psct (unused: withgres=False)

    // ---- workspace layout (4-byte words); ~182 MB total ----
    float* ws = (float*)d_ws;
    size_t off = 0;
    unsigned short* B16 = (unsigned short*)(ws + off);  off += (size_t)6 * NH / 2;
    float* att = ws + off;                              off += (size_t)6 * N_NODES;
    unsigned short* Xh  = (unsigned short*)(ws + off);  off += NH / 2;
    unsigned short* Wh1 = (unsigned short*)(ws + off);  off += HID * HID / 2;
    unsigned short* Wh2 = (unsigned short*)(ws + off);  off += HID * HID / 2;
    int*   ptr4   = (int*)(ws + off);                   off += (size_t)4 * PTRW;
    int*   table4 = (int*)(ws + off);                   off += (size_t)4 * TBL;
    int*   part4  = (int*)(ws + off);                   off += 4 * SB + 8;
    unsigned short* rank4 = (unsigned short*)(ws + off); off += (size_t)4 * NE / 2;
    off = (off + 3) & ~(size_t)3;                       // 16B align
    int2*     tmp4   = (int2*)(ws + off);               off += (size_t)8 * NE;
    unsigned* pairs4 = (unsigned*)(ws + off);           off += (size_t)4 * NE;
    // Aliases (lifetime-disjoint):
    //  hp16 (hprime out) = tmp4   — tmp4 dead after k4
    //  mid16 (fc1 out)   = pairs4 — pairs dead after last chain spmm
    unsigned short* hp16  = (unsigned short*)tmp4;
    unsigned short* mid16 = (unsigned short*)pairs4;

    dim3 blk(256);
    const int rg = (N_NODES * 32 + 255) / 256;  // 6250
    const int cg = (NH / 4 + 255) / 256;        // 6250
    const int wg = (HID * HID / 4 + 255) / 256; // 16

    // ---- conversions ----
    cvt_f2h_kernel<<<cg, blk, 0, stream>>>(X, Xh, NH / 4);
    cvt_f2h_kernel<<<wg, blk, 0, stream>>>(W1, Wh1, HID * HID / 4);
    cvt_f2h_kernel<<<wg, blk, 0, stream>>>(W2, Wh2, HID * HID / 4);

    // ---- batched counting-sort: 6 dispatches for all 4 operators ----
    k1_hist4<<<dim3(NBLK1, 4), blk, 0, stream>>>(
        op_rows[0], op_rows[1], op_rows[2], op_rows[3], table4, rank4);
    s1_partial4<<<dim3(SB, 4), blk, 0, stream>>>(table4, part4);
    s2_scan4<<<4, 1024, 0, stream>>>(part4);
    s3_add4<<<dim3(SB, 4), blk, 0, stream>>>(table4, part4);
    k3_scatter4<<<dim3(NBLK1, 4), blk, 0, stream>>>(
        op_rows[0], op_rows[1], op_rows[2], op_rows[3],
        op_cols[0], op_cols[1], op_cols[2], op_cols[3],
        op_vals[0], op_vals[1], op_vals[2], op_vals[3],
        rank4, table4, tmp4);
    k4_fine4<<<dim3(NBUK, 4), blk, 0, stream>>>(table4, tmp4, pairs4, ptr4);

    // ---- fused first-hop spmm (A,P1,P2,P3 all gather Xh; L2 reuse) ----
    spmm4_kernel<<<rg * 4, blk, 0, stream>>>(ptr4, pairs4, Xh, B16);

    // ---- chain hops 2,3 (A's CSR; fp16 in/out) ----
    spmm_chain_kernel<<<rg, blk, 0, stream>>>(ptr4, pairs4,
                                              B16 + 0 * (size_t)NH,
                                              B16 + 1 * (size_t)NH);
    spmm_chain_kernel<<<rg, blk, 0, stream>>>(ptr4, pairs4,
                                              B16 + 1 * (size_t)NH,
                                              B16 + 2 * (size_t)NH);

    // ---- attention, hprime, MFMA FCs ----
    attn_kernel<<<(N_NODES + 3) / 4, blk, 0, stream>>>(X, B16, a, att);
    hprime_kernel<<<(NH + 255) / 256, blk, 0, stream>>>(B16, att, hp16);
    fc_mfma_kernel<true ><<<1024, blk, 0, stream>>>(hp16,  Wh1, b1, mid16);
    fc_mfma_kernel<false><<<1024, blk, 0, stream>>>(mid16, Wh2, b2, d_out);
}

// Round 15
// 602.122 us; speedup vs baseline: 1.9011x; 1.0156x over previous
//
#include <hip/hip_runtime.h>
#include <hip/hip_fp16.h>

#define N_NODES 50000
#define HID 128
#define NH (N_NODES * HID)      // 6,400,000 elems per [N,HID] buffer
#define NE 1600000

#define EPB   8192              // edges per K1/K3 block
#define NBLK1 196               // ceil(NE / EPB)
#define NBUK  391               // ceil(N_NODES / 128) row buckets (128 rows each)
#define TBL   (NBUK * NBLK1)    // 76,636 scan table entries per op
#define SB    ((TBL + 255) / 256)  // 300 scan blocks per op
#define PTRW  (N_NODES + 2)     // words per rowptr array

#define TROWS 128               // rows per tail block
#define TPAD  136               // fp16 row pitch in LDS (272B: stride ≡ 4 words mod 32)

typedef _Float16 f16x8 __attribute__((ext_vector_type(8)));
typedef float    f32x4 __attribute__((ext_vector_type(4)));

// ---- fp16 helpers (RNE) ----
__device__ __forceinline__ float h2f(unsigned short u) {
    __half_raw r; r.x = u;
    __half h = r;
    return __half2float(h);
}
__device__ __forceinline__ unsigned short f2h(float f) {
    __half h = __float2half_rn(f);
    __half_raw r = h;
    return r.x;
}

// ===========================================================================
// K1 (batched 4 ops): per-block LDS histogram + per-edge rank.
// ===========================================================================
__global__ __launch_bounds__(256) void k1_hist4(
    const int* __restrict__ r0, const int* __restrict__ r1,
    const int* __restrict__ r2, const int* __restrict__ r3,
    int* __restrict__ table4, unsigned short* __restrict__ rank4)
{
    __shared__ int h[NBUK];
    int o = blockIdx.y, b = blockIdx.x, t = threadIdx.x;
    const int* rows = o == 0 ? r0 : o == 1 ? r1 : o == 2 ? r2 : r3;
    int* table = table4 + (size_t)o * TBL;
    unsigned short* rank = rank4 + (size_t)o * NE;

    for (int i = t; i < NBUK; i += 256) h[i] = 0;
    __syncthreads();
    int e0 = b * EPB;
    int e1 = min(e0 + EPB, NE);
    for (int e = e0 + t; e < e1; e += 256)
        rank[e] = (unsigned short)atomicAdd(&h[rows[e] >> 7], 1);
    __syncthreads();
    for (int i = t; i < NBUK; i += 256) table[i * NBLK1 + b] = h[i];
}

// ===========================================================================
// S1/S2/S3 (batched): hierarchical exclusive scan of each op's table
// ===========================================================================
__global__ __launch_bounds__(256) void s1_partial4(
    const int* __restrict__ table4, int* __restrict__ part4)
{
    __shared__ int red[256];
    int o = blockIdx.y, b = blockIdx.x, t = threadIdx.x;
    const int* table = table4 + (size_t)o * TBL;
    int idx = b * 256 + t;
    red[t] = (idx < TBL) ? table[idx] : 0;
    __syncthreads();
    #pragma unroll
    for (int s = 128; s > 0; s >>= 1) {
        if (t < s) red[t] += red[t + s];
        __syncthreads();
    }
    if (t == 0) part4[o * SB + b] = red[0];
}

__global__ __launch_bounds__(1024) void s2_scan4(int* __restrict__ part4)
{
    __shared__ int sh[1024];
    int o = blockIdx.x, t = threadIdx.x;
    int* part = part4 + o * SB;
    sh[t] = (t < SB) ? part[t] : 0;
    __syncthreads();
    for (int off = 1; off < 1024; off <<= 1) {
        int v = (t >= off) ? sh[t - off] : 0;
        __syncthreads();
        sh[t] += v;
        __syncthreads();
    }
    if (t < SB) part[t] = (t == 0) ? 0 : sh[t - 1];
}

__global__ __launch_bounds__(256) void s3_add4(
    int* __restrict__ table4, const int* __restrict__ part4)
{
    __shared__ int sh[256];
    int o = blockIdx.y, b = blockIdx.x, t = threadIdx.x;
    int* table = table4 + (size_t)o * TBL;
    int idx = b * 256 + t;
    int v = (idx < TBL) ? table[idx] : 0;
    sh[t] = v;
    __syncthreads();
    #pragma unroll
    for (int off = 1; off < 256; off <<= 1) {
        int u = (t >= off) ? sh[t - off] : 0;
        __syncthreads();
        sh[t] += u;
        __syncthreads();
    }
    int excl = (t == 0) ? 0 : sh[t - 1];
    if (idx < TBL) table[idx] = part4[o * SB + b] + excl;
}

// ===========================================================================
// K3 (batched): atomic-free scatter into bucket-partitioned tmp.
// tmp entry: .x = row&127, .y = col<<16 | fp16(val)
// ===========================================================================
__global__ __launch_bounds__(256) void k3_scatter4(
    const int* __restrict__ r0, const int* __restrict__ r1,
    const int* __restrict__ r2, const int* __restrict__ r3,
    const int* __restrict__ c0, const int* __restrict__ c1,
    const int* __restrict__ c2, const int* __restrict__ c3,
    const float* __restrict__ v0, const float* __restrict__ v1,
    const float* __restrict__ v2, const float* __restrict__ v3,
    const unsigned short* __restrict__ rank4,
    const int* __restrict__ table4, int2* __restrict__ tmp4)
{
    __shared__ int base[NBUK];
    int o = blockIdx.y, b = blockIdx.x, t = threadIdx.x;
    const int*   rows = o == 0 ? r0 : o == 1 ? r1 : o == 2 ? r2 : r3;
    const int*   cols = o == 0 ? c0 : o == 1 ? c1 : o == 2 ? c2 : c3;
    const float* vals = o == 0 ? v0 : o == 1 ? v1 : o == 2 ? v2 : v3;
    const int* table = table4 + (size_t)o * TBL;
    const unsigned short* rank = rank4 + (size_t)o * NE;
    int2* tmp = tmp4 + (size_t)o * NE;

    for (int i = t; i < NBUK; i += 256) base[i] = table[i * NBLK1 + b];
    __syncthreads();
    int e0 = b * EPB;
    int e1 = min(e0 + EPB, NE);
    for (int e = e0 + t; e < e1; e += 256) {
        int r = rows[e];
        int pos = base[r >> 7] + (int)rank[e];
        unsigned pk = ((unsigned)cols[e] << 16) | (unsigned)f2h(vals[e]);
        tmp[pos] = make_int2(r & 127, (int)pk);
    }
}

// ===========================================================================
// K4 (batched): per-bucket fine sort -> packed pairs (4B) + rowptr.
// ===========================================================================
__global__ __launch_bounds__(256) void k4_fine4(
    const int* __restrict__ table4, const int2* __restrict__ tmp4,
    unsigned* __restrict__ pairs4, int* __restrict__ ptr4)
{
    __shared__ int cnt[128];
    __shared__ int sh[256];
    __shared__ int nxt[128];
    int o = blockIdx.y, k = blockIdx.x, t = threadIdx.x;
    const int* table = table4 + (size_t)o * TBL;
    const int2* tmp = tmp4 + (size_t)o * NE;
    unsigned* pairs = pairs4 + (size_t)o * NE;
    int* rowptr = ptr4 + (size_t)o * PTRW;

    if (t < 128) cnt[t] = 0;
    __syncthreads();
    int base = table[k * NBLK1];
    int end  = (k == NBUK - 1) ? NE : table[(k + 1) * NBLK1];
    for (int e = base + t; e < end; e += 256)
        atomicAdd(&cnt[tmp[e].x], 1);
    __syncthreads();
    sh[t] = (t < 128) ? cnt[t] : 0;
    __syncthreads();
    #pragma unroll
    for (int off = 1; off < 256; off <<= 1) {
        int v = (t >= off) ? sh[t - off] : 0;
        __syncthreads();
        sh[t] += v;
        __syncthreads();
    }
    if (t < 128) {
        int excl = (t == 0) ? 0 : sh[t - 1];
        nxt[t] = base + excl;
        int row = k * 128 + t;
        if (row < N_NODES) rowptr[row] = base + excl;
    }
    if (k == NBUK - 1 && t == 255) rowptr[N_NODES] = NE;
    __syncthreads();
    for (int e = base + t; e < end; e += 256) {
        int2 p = tmp[e];
        int pos = atomicAdd(&nxt[p.x], 1);
        pairs[pos] = (unsigned)p.y;
    }
}

// ===========================================================================
// cvt: fp32 -> fp16 (RNE), n4 = element count / 4
// ===========================================================================
__global__ __launch_bounds__(256) void cvt_f2h_kernel(
    const float* __restrict__ in, unsigned short* __restrict__ out, int n4)
{
    int i = blockIdx.x * 256 + threadIdx.x;
    if (i >= n4) return;
    float4 v = ((const float4*)in)[i];
    ushort4 o;
    o.x = f2h(v.x); o.y = f2h(v.y); o.z = f2h(v.z); o.w = f2h(v.w);
    ((ushort4*)out)[i] = o;
}

// ===========================================================================
// SpMM row core: packed 4B edges (col<<16|fp16 val), fp16 gather,
// fp32 accumulate, fp16 store. 32 lanes per row; 4-way unrolled.
// ===========================================================================
__device__ __forceinline__ void spmm_row(
    const unsigned short* __restrict__ xh, const unsigned* __restrict__ pairs,
    int start, int end, int sub, bool do_abs,
    unsigned short* __restrict__ yrow)
{
    const ushort4* x4 = (const ushort4*)xh + sub;  // row stride = 32 ushort4

    float4 a0 = {0,0,0,0}, a1 = {0,0,0,0};
    float4 a2 = {0,0,0,0}, a3 = {0,0,0,0};

    #define EDGE_P(P, A) { \
        unsigned _p = (P); \
        float _v = h2f((unsigned short)(_p & 0xFFFFu)); \
        ushort4 _x = x4[(size_t)(_p >> 16) * 32]; \
        A.x += _v * h2f(_x.x); \
        A.y += _v * h2f(_x.y); \
        A.z += _v * h2f(_x.z); \
        A.w += _v * h2f(_x.w); }

    int e = start;
    for (; e + 3 < end; e += 4) {
        unsigned p0 = pairs[e];
        unsigned p1 = pairs[e + 1];
        unsigned p2 = pairs[e + 2];
        unsigned p3 = pairs[e + 3];
        EDGE_P(p0, a0); EDGE_P(p1, a1); EDGE_P(p2, a2); EDGE_P(p3, a3);
    }
    for (; e < end; ++e) {
        EDGE_P(pairs[e], a0);
    }
    #undef EDGE_P

    float4 acc;
    acc.x = (a0.x + a1.x) + (a2.x + a3.x);
    acc.y = (a0.y + a1.y) + (a2.y + a3.y);
    acc.z = (a0.z + a1.z) + (a2.z + a3.z);
    acc.w = (a0.w + a1.w) + (a2.w + a3.w);
    if (do_abs) {
        acc.x = fabsf(acc.x); acc.y = fabsf(acc.y);
        acc.z = fabsf(acc.z); acc.w = fabsf(acc.w);
    }
    ushort4 o;
    o.x = f2h(acc.x); o.y = f2h(acc.y); o.z = f2h(acc.z); o.w = f2h(acc.w);
    ((ushort4*)yrow)[sub] = o;
}

// ===========================================================================
// Fused first-hop SpMM: 4 operators (A, P1, P2, P3), all gathering Xh.
// bid & 3 = op (adjacent blocks = different ops -> L2 temporal reuse of Xh).
// ===========================================================================
__global__ __launch_bounds__(256) void spmm4_kernel(
    const int* __restrict__ ptr4, const unsigned* __restrict__ pairs4,
    const unsigned short* __restrict__ Xh, unsigned short* __restrict__ B16)
{
    int bid = blockIdx.x;
    int op  = bid & 3;
    int rb  = bid >> 2;
    int r   = rb * 8 + (threadIdx.x >> 5);
    int sub = threadIdx.x & 31;
    if (r >= N_NODES) return;

    const int*      ptr   = ptr4 + (size_t)op * PTRW;
    const unsigned* pairs = pairs4 + (size_t)op * NE;
    int dst = op ? op + 2 : 0;
    unsigned short* yrow = B16 + (size_t)dst * NH + (size_t)r * HID;

    spmm_row(Xh, pairs, ptr[r], ptr[r + 1], sub, op != 0, yrow);
}

// ===========================================================================
// Chain-hop SpMM (A's CSR, no abs): src16 -> dst16.
// ===========================================================================
__global__ __launch_bounds__(256) void spmm_chain_kernel(
    const int* __restrict__ ptr, const unsigned* __restrict__ pairs,
    const unsigned short* __restrict__ src16, unsigned short* __restrict__ dst16)
{
    int t   = blockIdx.x * 256 + threadIdx.x;
    int r   = t >> 5;
    int sub = t & 31;
    if (r >= N_NODES) return;
    spmm_row(src16, pairs, ptr[r], ptr[r + 1], sub, false,
             dst16 + (size_t)r * HID);
}

// ===========================================================================
// Attention: e[n,b] = dot(relu(pair_b[n]), a); att = softmax over b (6).
// ===========================================================================
__global__ __launch_bounds__(256) void attn_kernel(
    const float* __restrict__ X, const unsigned short* __restrict__ B16,
    const float* __restrict__ a, float* __restrict__ att)
{
    int wid  = (blockIdx.x * 256 + threadIdx.x) >> 6;
    int lane = threadIdx.x & 63;
    if (wid >= N_NODES) return;

    const float4 av = ((const float4*)a)[lane];
    float e[6];

    if (wid < N_NODES / 2) {
        const float4 p = ((const float4*)(X + (size_t)wid * 256))[lane];
        float s = fmaxf(p.x, 0.f) * av.x + fmaxf(p.y, 0.f) * av.y +
                  fmaxf(p.z, 0.f) * av.z + fmaxf(p.w, 0.f) * av.w;
        #pragma unroll
        for (int m = 1; m < 64; m <<= 1) s += __shfl_xor(s, m);
        #pragma unroll
        for (int b = 0; b < 6; ++b) e[b] = s;
    } else {
        int m = 2 * wid - N_NODES;
        #pragma unroll
        for (int b = 0; b < 6; ++b) {
            ushort4 u = ((const ushort4*)(B16 + (size_t)b * NH +
                                          (size_t)m * HID))[lane];
            float s = fmaxf(h2f(u.x), 0.f) * av.x + fmaxf(h2f(u.y), 0.f) * av.y +
                      fmaxf(h2f(u.z), 0.f) * av.z + fmaxf(h2f(u.w), 0.f) * av.w;
            #pragma unroll
            for (int k = 1; k < 64; k <<= 1) s += __shfl_xor(s, k);
            e[b] = s;
        }
    }

    if (lane == 0) {
        float mx = e[0];
        #pragma unroll
        for (int b = 1; b < 6; ++b) mx = fmaxf(mx, e[b]);
        float ex[6], sum = 0.f;
        #pragma unroll
        for (int b = 0; b < 6; ++b) { ex[b] = expf(e[b] - mx); sum += ex[b]; }
        float inv = 1.f / sum;
        #pragma unroll
        for (int b = 0; b < 6; ++b) att[(size_t)wid * 6 + b] = ex[b] * inv;
    }
}

// ===========================================================================
// Fused tail: hprime -> LDS, MFMA FC1 -> LDS, MFMA FC2 -> d_out.
// One block = 128 rows (row-local chain). LDS pitch 136 fp16 (272B: row
// stride ≡ 4 words mod 32 -> ≤2-way bank aliasing, free per m136).
// MFMA fragment mapping identical to the verified r12 fc_mfma kernel.
// ===========================================================================
__global__ __launch_bounds__(256) void tail_kernel(
    const unsigned short* __restrict__ B16, const float* __restrict__ att,
    const unsigned short* __restrict__ Wh1, const float* __restrict__ b1,
    const unsigned short* __restrict__ Wh2, const float* __restrict__ b2,
    float* __restrict__ outp)
{
    __shared__ __align__(16) unsigned short hp[TROWS][TPAD];
    __shared__ __align__(16) unsigned short md[TROWS][TPAD];
    __shared__ float att_l[TROWS * 6];

    const int t  = threadIdx.x;
    const int n0 = blockIdx.x * TROWS;

    // ---- stage att for this row block ----
    for (int i = t; i < TROWS * 6; i += 256)
        att_l[i] = att[min((size_t)n0 * 6 + i, (size_t)N_NODES * 6 - 1)];
    __syncthreads();

    // ---- phase 1: hprime -> hp LDS ----
    #pragma unroll 2
    for (int i = 0; i < (TROWS * HID) / 256; ++i) {
        int idx = i * 256 + t;
        int rl = idx >> 7, q = idx & 127;
        int n = min(n0 + rl, N_NODES - 1);
        float s = 0.f;
        #pragma unroll
        for (int p = 0; p < 6; ++p) {
            int f = p * HID + q;
            int j = f % 6;
            int ii = f / 6;
            s += att_l[rl * 6 + p] *
                 h2f(B16[(size_t)j * NH + (size_t)n * HID + ii]);
        }
        hp[rl][q] = f2h(s * (1.0f / 6.0f));
    }
    __syncthreads();

    const int lane = t & 63;
    const int wv   = t >> 6;       // 0..3
    const int lr   = lane & 15;    // M/N fragment index
    const int kg   = lane >> 4;    // k-group 0..3

    // ---- phase 2: FC1 hp(LDS) x W1 -> md(LDS) ----
    #pragma unroll
    for (int ci = 0; ci < 2; ++ci) {
        int cb = wv * 2 + ci;             // col-block 0..7
        int o  = cb * 16 + lr;
        f16x8 bf[4];
        #pragma unroll
        for (int ks = 0; ks < 4; ++ks)
            bf[ks] = *(const f16x8*)(Wh1 + (size_t)o * HID + ks * 32 + kg * 8);
        float bo = b1[o];
        #pragma unroll
        for (int rt = 0; rt < 8; ++rt) {
            f32x4 acc = {0.f, 0.f, 0.f, 0.f};
            #pragma unroll
            for (int ks = 0; ks < 4; ++ks) {
                f16x8 af = *(const f16x8*)&hp[rt * 16 + lr][ks * 32 + kg * 8];
                acc = __builtin_amdgcn_mfma_f32_16x16x32_f16(af, bf[ks], acc,
                                                             0, 0, 0);
            }
            #pragma unroll
            for (int j = 0; j < 4; ++j) {
                float v = acc[j] + bo;
                v = v > 0.f ? v : 0.01f * v;
                md[rt * 16 + kg * 4 + j][o] = f2h(v);
            }
        }
    }
    __syncthreads();

    // ---- phase 3: FC2 md(LDS) x W2 -> global out ----
    #pragma unroll
    for (int ci = 0; ci < 2; ++ci) {
        int cb = wv * 2 + ci;
        int o  = cb * 16 + lr;
        f16x8 bf[4];
        #pragma unroll
        for (int ks = 0; ks < 4; ++ks)
            bf[ks] = *(const f16x8*)(Wh2 + (size_t)o * HID + ks * 32 + kg * 8);
        float bo = b2[o];
        #pragma unroll
        for (int rt = 0; rt < 8; ++rt) {
            f32x4 acc = {0.f, 0.f, 0.f, 0.f};
            #pragma unroll
            for (int ks = 0; ks < 4; ++ks) {
                f16x8 af = *(const f16x8*)&md[rt * 16 + lr][ks * 32 + kg * 8];
                acc = __builtin_amdgcn_mfma_f32_16x16x32_f16(af, bf[ks], acc,
                                                             0, 0, 0);
            }
            #pragma unroll
            for (int j = 0; j < 4; ++j) {
                int n = n0 + rt * 16 + kg * 4 + j;
                if (n < N_NODES) {
                    float v = acc[j] + bo;
                    v = v > 0.f ? v : 0.01f * v;
                    outp[(size_t)n * HID + o] = v;
                }
            }
        }
    }
}

// ===========================================================================
extern "C" void kernel_launch(void* const* d_in, const int* in_sizes, int n_in,
                              void* d_out, int out_size, void* d_ws, size_t ws_size,
                              hipStream_t stream)
{
    const float* X  = (const float*)d_in[0];
    const float* a  = (const float*)d_in[1];
    const float* W1 = (const float*)d_in[2];
    const float* b1 = (const float*)d_in[3];
    const float* W2 = (const float*)d_in[4];
    const float* b2 = (const float*)d_in[5];
    const int*   op_rows[4] = { (const int*)d_in[6],  (const int*)d_in[9],
                                (const int*)d_in[12], (const int*)d_in[15] };
    const int*   op_cols[4] = { (const int*)d_in[7],  (const int*)d_in[10],
                                (const int*)d_in[13], (const int*)d_in[16] };
    const float* op_vals[4] = { (const float*)d_in[8],  (const float*)d_in[11],
                                (const float*)d_in[14], (const float*)d_in[17] };
    // d_in[18..20] = Psct (unused: withgres=False)

    // ---- workspace layout (4-byte words) ----
    float* ws = (float*)d_ws;
    size_t off = 0;
    unsigned short* B16 = (unsigned short*)(ws + off);  off += (size_t)6 * NH / 2;
    float* att = ws + off;                              off += (size_t)6 * N_NODES;
    unsigned short* Xh  = (unsigned short*)(ws + off);  off += NH / 2;
    unsigned short* Wh1 = (unsigned short*)(ws + off);  off += HID * HID / 2;
    unsigned short* Wh2 = (unsigned short*)(ws + off);  off += HID * HID / 2;
    int*   ptr4   = (int*)(ws + off);                   off += (size_t)4 * PTRW;
    int*   table4 = (int*)(ws + off);                   off += (size_t)4 * TBL;
    int*   part4  = (int*)(ws + off);                   off += 4 * SB + 8;
    unsigned short* rank4 = (unsigned short*)(ws + off); off += (size_t)4 * NE / 2;
    off = (off + 3) & ~(size_t)3;                       // 16B align
    int2*     tmp4   = (int2*)(ws + off);               off += (size_t)8 * NE;
    unsigned* pairs4 = (unsigned*)(ws + off);           off += (size_t)4 * NE;

    dim3 blk(256);
    const int rg = (N_NODES * 32 + 255) / 256;  // 6250
    const int cg = (NH / 4 + 255) / 256;        // 6250
    const int wg = (HID * HID / 4 + 255) / 256; // 16
    const int tg = (N_NODES + TROWS - 1) / TROWS; // 391

    // ---- conversions ----
    cvt_f2h_kernel<<<cg, blk, 0, stream>>>(X, Xh, NH / 4);
    cvt_f2h_kernel<<<wg, blk, 0, stream>>>(W1, Wh1, HID * HID / 4);
    cvt_f2h_kernel<<<wg, blk, 0, stream>>>(W2, Wh2, HID * HID / 4);

    // ---- batched counting-sort: 6 dispatches for all 4 operators ----
    k1_hist4<<<dim3(NBLK1, 4), blk, 0, stream>>>(
        op_rows[0], op_rows[1], op_rows[2], op_rows[3], table4, rank4);
    s1_partial4<<<dim3(SB, 4), blk, 0, stream>>>(table4, part4);
    s2_scan4<<<4, 1024, 0, stream>>>(part4);
    s3_add4<<<dim3(SB, 4), blk, 0, stream>>>(table4, part4);
    k3_scatter4<<<dim3(NBLK1, 4), blk, 0, stream>>>(
        op_rows[0], op_rows[1], op_rows[2], op_rows[3],
        op_cols[0], op_cols[1], op_cols[2], op_cols[3],
        op_vals[0], op_vals[1], op_vals[2], op_vals[3],
        rank4, table4, tmp4);
    k4_fine4<<<dim3(NBUK, 4), blk, 0, stream>>>(table4, tmp4, pairs4, ptr4);

    // ---- fused first-hop spmm (A,P1,P2,P3 all gather Xh; L2 reuse) ----
    spmm4_kernel<<<rg * 4, blk, 0, stream>>>(ptr4, pairs4, Xh, B16);

    // ---- chain hops 2,3 (A's CSR; fp16 in/out) ----
    spmm_chain_kernel<<<rg, blk, 0, stream>>>(ptr4, pairs4,
                                              B16 + 0 * (size_t)NH,
                                              B16 + 1 * (size_t)NH);
    spmm_chain_kernel<<<rg, blk, 0, stream>>>(ptr4, pairs4,
                                              B16 + 1 * (size_t)NH,
                                              B16 + 2 * (size_t)NH);

    // ---- attention, fused hprime+FC1+FC2 ----
    attn_kernel<<<(N_NODES + 3) / 4, blk, 0, stream>>>(X, B16, a, att);
    tail_kernel<<<tg, blk, 0, stream>>>(B16, att, Wh1, b1, Wh2, b2,
                                        (float*)d_out);
}